// Round 1
// baseline (465.730 us; speedup 1.0000x reference)
//
#include <hip/hip_runtime.h>

// Problem constants
#define B_ 4
#define L_ 512
#define T_ 4096
#define NH_ 16
#define HD_ 64
// HID = 1024, MAX_POS = 4096

using f32x4 = __attribute__((ext_vector_type(4))) float;
using bf16x8 = __attribute__((ext_vector_type(8))) short;
using u32x4 = __attribute__((ext_vector_type(4))) unsigned int;

__device__ __forceinline__ unsigned short f2bf(float x) {
  unsigned int u = __builtin_bit_cast(unsigned int, x);
  u += 0x7fffu + ((u >> 16) & 1u);
  return (unsigned short)(u >> 16);
}

__device__ __forceinline__ u32x4 cvt8(const float4& a, const float4& b) {
  u32x4 r;
  r[0] = (unsigned)f2bf(a.x) | ((unsigned)f2bf(a.y) << 16);
  r[1] = (unsigned)f2bf(a.z) | ((unsigned)f2bf(a.w) << 16);
  r[2] = (unsigned)f2bf(b.x) | ((unsigned)f2bf(b.y) << 16);
  r[3] = (unsigned)f2bf(b.z) | ((unsigned)f2bf(b.w) << 16);
  return r;
}

__device__ __forceinline__ void gload16(const void* g, void* l) {
  __builtin_amdgcn_global_load_lds(
      (const __attribute__((address_space(1))) unsigned int*)g,
      (__attribute__((address_space(3))) unsigned int*)l, 16, 0, 0);
}

#define BC8(x) __builtin_bit_cast(bf16x8, (x))

// cos/sin tables: [4096 pos][32] each (emb duplicates freqs, so 32 suffices)
__global__ void rope_table(float* __restrict__ cost, float* __restrict__ sint) {
  const int idx = blockIdx.x * 256 + threadIdx.x;  // 4096*32 total
  const int pos = idx >> 5, i = idx & 31;
  const float inv = 1.0f / powf(10000.0f, (float)(2 * i) * (1.0f / 64.0f));
  const float f = (float)pos * inv;
  cost[idx] = cosf(f);
  sint[idx] = sinf(f);
}

// C = A @ W.T + bias, M x 1024, K = 1024.  128x128 tile, BK=32, 4 waves.
// EPI: 0=Q(rope->[b][h][l][d] bf16) 1=K(rope->[b][h][t][d] bf16)
//      2=V(->[b][h][d][t] bf16)     3=out(f32 row-major)
template <int EPI, bool ABF>
__global__ __launch_bounds__(256, 2) void gemm_proj(
    const void* __restrict__ Aptr, const float* __restrict__ W,
    const float* __restrict__ bias, void* __restrict__ outp,
    const float* __restrict__ cost, const float* __restrict__ sint,
    const int* __restrict__ ts) {
  __shared__ u32x4 lsA[2][512];  // chunk-major: [kg 0..3][row 0..127] of 8 bf16
  __shared__ u32x4 lsB[2][512];
  const int tid = threadIdx.x;
  const int mt = blockIdx.x >> 3, nt = blockIdx.x & 7;
  const int mBase = mt << 7, nBase = nt << 7;
  const int lane = tid & 63, wid = tid >> 6;
  const int wr = wid >> 1, wc = wid & 1;
  const int lr = lane & 15, lg = lane >> 4;
  const int crow0 = tid >> 2, ckg = tid & 3;

  const float* Af = (const float*)Aptr;
  const unsigned short* Ab = (const unsigned short*)Aptr;

  f32x4 acc[4][4];
#pragma unroll
  for (int m = 0; m < 4; ++m)
#pragma unroll
    for (int n = 0; n < 4; ++n) acc[m][n] = (f32x4){0.f, 0.f, 0.f, 0.f};

  const size_t arow0 = (size_t)(mBase + crow0) * 1024 + ckg * 8;
  const size_t arow1 = (size_t)(mBase + crow0 + 64) * 1024 + ckg * 8;
  const size_t brow0 = (size_t)(nBase + crow0) * 1024 + ckg * 8;
  const size_t brow1 = (size_t)(nBase + crow0 + 64) * 1024 + ckg * 8;
  const int dsti0 = ckg * 128 + crow0;
  const int dsti1 = ckg * 128 + crow0 + 64;

  // prologue: stage kt=0
  if (ABF) {
    lsA[0][dsti0] = *(const u32x4*)(Ab + arow0);
    lsA[0][dsti1] = *(const u32x4*)(Ab + arow1);
  } else {
    float4 x0 = *(const float4*)(Af + arow0), x1 = *(const float4*)(Af + arow0 + 4);
    float4 x2 = *(const float4*)(Af + arow1), x3 = *(const float4*)(Af + arow1 + 4);
    lsA[0][dsti0] = cvt8(x0, x1);
    lsA[0][dsti1] = cvt8(x2, x3);
  }
  {
    float4 y0 = *(const float4*)(W + brow0), y1 = *(const float4*)(W + brow0 + 4);
    float4 y2 = *(const float4*)(W + brow1), y3 = *(const float4*)(W + brow1 + 4);
    lsB[0][dsti0] = cvt8(y0, y1);
    lsB[0][dsti1] = cvt8(y2, y3);
  }
  __syncthreads();

  int buf = 0;
  for (int kt = 0; kt < 32; ++kt) {
    u32x4 pa0, pa1;
    float4 fa0, fa1, fa2, fa3, fb0, fb1, fb2, fb3;
    const bool pre = (kt < 31);
    if (pre) {
      const int ko = (kt + 1) * 32;
      if (ABF) {
        pa0 = *(const u32x4*)(Ab + arow0 + ko);
        pa1 = *(const u32x4*)(Ab + arow1 + ko);
      } else {
        fa0 = *(const float4*)(Af + arow0 + ko);
        fa1 = *(const float4*)(Af + arow0 + ko + 4);
        fa2 = *(const float4*)(Af + arow1 + ko);
        fa3 = *(const float4*)(Af + arow1 + ko + 4);
      }
      fb0 = *(const float4*)(W + brow0 + ko);
      fb1 = *(const float4*)(W + brow0 + ko + 4);
      fb2 = *(const float4*)(W + brow1 + ko);
      fb3 = *(const float4*)(W + brow1 + ko + 4);
    }
    const u32x4* As = lsA[buf];
    const u32x4* Bs = lsB[buf];
    bf16x8 af[4], bfr[4];
#pragma unroll
    for (int m = 0; m < 4; ++m) af[m] = BC8(As[lg * 128 + wr * 64 + m * 16 + lr]);
#pragma unroll
    for (int n = 0; n < 4; ++n) bfr[n] = BC8(Bs[lg * 128 + wc * 64 + n * 16 + lr]);
#pragma unroll
    for (int m = 0; m < 4; ++m)
#pragma unroll
      for (int n = 0; n < 4; ++n)
        acc[m][n] = __builtin_amdgcn_mfma_f32_16x16x32_bf16(af[m], bfr[n], acc[m][n], 0, 0, 0);
    if (pre) {
      u32x4* wA = lsA[buf ^ 1];
      u32x4* wB = lsB[buf ^ 1];
      if (ABF) {
        wA[dsti0] = pa0;
        wA[dsti1] = pa1;
      } else {
        wA[dsti0] = cvt8(fa0, fa1);
        wA[dsti1] = cvt8(fa2, fa3);
      }
      wB[dsti0] = cvt8(fb0, fb1);
      wB[dsti1] = cvt8(fb2, fb3);
    }
    __syncthreads();
    buf ^= 1;
  }

  // ---- epilogue ----
  float bv[4];
#pragma unroll
  for (int n = 0; n < 4; ++n) bv[n] = bias[nBase + wc * 64 + n * 16 + lr];

  if (EPI == 3) {
    float* Of = (float*)outp;
#pragma unroll
    for (int m = 0; m < 4; ++m)
#pragma unroll
      for (int r = 0; r < 4; ++r) {
        const int gR = mBase + wr * 64 + m * 16 + lg * 4 + r;
#pragma unroll
        for (int n = 0; n < 4; ++n)
          Of[(size_t)gR * 1024 + nBase + wc * 64 + n * 16 + lr] = acc[m][n][r] + bv[n];
      }
  } else if (EPI == 2) {
    unsigned short* Vo = (unsigned short*)outp;
    const int h = (nBase >> 6) + wc;
#pragma unroll
    for (int m = 0; m < 4; ++m) {
      const int r0 = mBase + wr * 64 + m * 16 + lg * 4;
      const int b = r0 >> 12, t = r0 & 4095;
#pragma unroll
      for (int n = 0; n < 4; ++n) {
        const int d = n * 16 + lr;
        ushort4 pk;
        pk.x = f2bf(acc[m][n][0] + bv[n]);
        pk.y = f2bf(acc[m][n][1] + bv[n]);
        pk.z = f2bf(acc[m][n][2] + bv[n]);
        pk.w = f2bf(acc[m][n][3] + bv[n]);
        *(ushort4*)(Vo + (((size_t)(b * NH_ + h)) * HD_ + d) * (size_t)T_ + t) = pk;
      }
    }
  } else {
    unsigned short* Qo = (unsigned short*)outp;
    const int h = (nBase >> 6) + wc;
    const int P = (EPI == 0) ? L_ : T_;
#pragma unroll
    for (int m = 0; m < 4; ++m) {
#pragma unroll
      for (int r = 0; r < 4; ++r) {
        const int gR = mBase + wr * 64 + m * 16 + lg * 4 + r;
        int b2, p2, pos;
        if (EPI == 0) {
          b2 = gR >> 9;
          p2 = gR & 511;
          pos = (int)(((float)p2 * 4095.0f) / 511.0f);  // matches jnp f32 mul/div + trunc
        } else {
          b2 = gR >> 12;
          p2 = gR & 4095;
          pos = ts[gR];
        }
        const float* cp = cost + pos * 32;
        const float* sp = sint + pos * 32;
        const size_t obase = (((size_t)(b2 * NH_ + h)) * P + p2) * HD_;
#pragma unroll
        for (int n = 0; n < 2; ++n) {
          const int d = n * 16 + lr;
          const float x1 = acc[m][n][r] + bv[n];
          const float x2 = acc[m][n + 2][r] + bv[n + 2];
          const float c = cp[d], s = sp[d];
          Qo[obase + d] = f2bf(x1 * c - x2 * s);
          Qo[obase + d + 32] = f2bf(x2 * c + x1 * s);
        }
      }
    }
  }
}

// Flash attention. Grid: (b,h,ltile) = 4*16*8 = 512 blocks, 256 thr (4 waves x 16 rows).
// Q: [b][h][l][d] bf16; K: [b][h][t][d] bf16; V: [b][h][d][t] bf16; O: [b*l][1024] bf16.
__global__ __launch_bounds__(256, 2) void attn_kernel(
    const unsigned short* __restrict__ Q, const unsigned short* __restrict__ K,
    const unsigned short* __restrict__ V, const int* __restrict__ mask,
    unsigned short* __restrict__ O) {
  __shared__ u32x4 QP[512];  // 8KB: Q chunks [kg 0..7][row 0..63]; reused as per-wave P after
  __shared__ u32x4 Ks[512];  // 8KB: [kg 0..7][t 0..63]
  __shared__ u32x4 Vs[512];  // 8KB: [tg 0..7][d 0..63]
  const int tid = threadIdx.x, lane = tid & 63, w = tid >> 6;
  const int lr = lane & 15, lg = lane >> 4;
  const int lt = blockIdx.x & 7, bh = blockIdx.x >> 3;
  const int b = bh >> 4, h = bh & 15;
  const int l0 = lt << 6;

#pragma unroll
  for (int i = 0; i < 2; ++i) {
    const int li = w * 2 + i;
    gload16(Q + ((size_t)bh * L_ + l0 + lane) * HD_ + li * 8, (unsigned short*)QP + li * 512);
  }
  __syncthreads();
  bf16x8 qf[2];
#pragma unroll
  for (int ks2 = 0; ks2 < 2; ++ks2)
    qf[ks2] = BC8(QP[(ks2 * 4 + lg) * 64 + w * 16 + lr]);
  // qf reads drain at the first in-loop barrier before any wave writes P into QP.

  f32x4 po[4];
#pragma unroll
  for (int n = 0; n < 4; ++n) po[n] = (f32x4){0.f, 0.f, 0.f, 0.f};
  float mrun[4], lrun[4];
#pragma unroll
  for (int r = 0; r < 4; ++r) { mrun[r] = -1e30f; lrun[r] = 0.f; }

  unsigned short* Pw = (unsigned short*)QP + w * 1024;  // 16x64 bf16, XOR-swizzled
  const u32x4* Pr = QP + w * 128;
  const int* mrow = mask + (size_t)b * T_;

  for (int it = 0; it < 64; ++it) {
    const int t0 = it << 6;
#pragma unroll
    for (int i = 0; i < 2; ++i) {
      const int li = w * 2 + i;
      gload16(K + ((size_t)bh * T_ + t0 + lane) * HD_ + li * 8, (unsigned short*)Ks + li * 512);
      gload16(V + ((size_t)bh * HD_ + lane) * T_ + t0 + li * 8, (unsigned short*)Vs + li * 512);
    }
    __syncthreads();

    f32x4 s[4];
#pragma unroll
    for (int n = 0; n < 4; ++n) s[n] = (f32x4){0.f, 0.f, 0.f, 0.f};
#pragma unroll
    for (int ks2 = 0; ks2 < 2; ++ks2) {
#pragma unroll
      for (int n = 0; n < 4; ++n) {
        bf16x8 kb = BC8(Ks[(ks2 * 4 + lg) * 64 + n * 16 + lr]);
        s[n] = __builtin_amdgcn_mfma_f32_16x16x32_bf16(qf[ks2], kb, s[n], 0, 0, 0);
      }
    }
    float mb[4];
#pragma unroll
    for (int n = 0; n < 4; ++n) mb[n] = mrow[t0 + n * 16 + lr] ? 0.f : -1e30f;
#pragma unroll
    for (int n = 0; n < 4; ++n)
#pragma unroll
      for (int r = 0; r < 4; ++r) s[n][r] = s[n][r] * 0.125f + mb[n];
#pragma unroll
    for (int r = 0; r < 4; ++r) {
      float x = fmaxf(fmaxf(s[0][r], s[1][r]), fmaxf(s[2][r], s[3][r]));
      x = fmaxf(x, __shfl_xor(x, 1));
      x = fmaxf(x, __shfl_xor(x, 2));
      x = fmaxf(x, __shfl_xor(x, 4));
      x = fmaxf(x, __shfl_xor(x, 8));
      const float mnew = fmaxf(mrun[r], x);
      const float sc = __expf(mrun[r] - mnew);
      mrun[r] = mnew;
      float rs = 0.f;
#pragma unroll
      for (int n = 0; n < 4; ++n) {
        const float p = __expf(s[n][r] - mnew);
        s[n][r] = p;
        rs += p;
      }
      rs += __shfl_xor(rs, 1);
      rs += __shfl_xor(rs, 2);
      rs += __shfl_xor(rs, 4);
      rs += __shfl_xor(rs, 8);
      lrun[r] = lrun[r] * sc + rs;
#pragma unroll
      for (int n = 0; n < 4; ++n) po[n][r] *= sc;
    }
    // P -> LDS (rows l = lg*4+r, cols t = n*16+lr), granule XOR-swizzle
#pragma unroll
    for (int r = 0; r < 4; ++r) {
      const int l = lg * 4 + r;
      const int lb = l * 64, swz = l & 7;
#pragma unroll
      for (int n = 0; n < 4; ++n) {
        const int t = n * 16 + lr;
        Pw[lb + (((t >> 3) ^ swz) << 3) + (t & 7)] = f2bf(s[n][r]);
      }
    }
    // PV: O += P @ V^T(d-major)
#pragma unroll
    for (int ks2 = 0; ks2 < 2; ++ks2) {
      const int g = ks2 * 4 + lg;
      bf16x8 pa = BC8(Pr[lr * 8 + (g ^ (lr & 7))]);
#pragma unroll
      for (int n = 0; n < 4; ++n) {
        bf16x8 vb = BC8(Vs[g * 64 + n * 16 + lr]);
        po[n] = __builtin_amdgcn_mfma_f32_16x16x32_bf16(pa, vb, po[n], 0, 0, 0);
      }
    }
    __syncthreads();
  }
#pragma unroll
  for (int r = 0; r < 4; ++r) {
    const float inv = 1.0f / lrun[r];
    const int gl = l0 + w * 16 + lg * 4 + r;
    unsigned short* orow = O + ((size_t)b * L_ + gl) * 1024 + h * HD_;
#pragma unroll
    for (int n = 0; n < 4; ++n) orow[n * 16 + lr] = f2bf(po[n][r] * inv);
  }
}

extern "C" void kernel_launch(void* const* d_in, const int* in_sizes, int n_in,
                              void* d_out, int out_size, void* d_ws, size_t ws_size,
                              hipStream_t stream) {
  const float* latents = (const float*)d_in[0];
  const float* target = (const float*)d_in[1];
  const int* mask = (const int*)d_in[2];
  const int* ts = (const int*)d_in[3];
  const float* Wq = (const float*)d_in[4];
  const float* bq = (const float*)d_in[5];
  const float* Wk = (const float*)d_in[6];
  const float* bk = (const float*)d_in[7];
  const float* Wv = (const float*)d_in[8];
  const float* bv = (const float*)d_in[9];
  const float* Wo = (const float*)d_in[10];
  const float* bo = (const float*)d_in[11];
  float* out = (float*)d_out;

  // ws layout (73 MB total):
  char* ws = (char*)d_ws;
  float* cost = (float*)ws;                                   // 512 KB
  float* sint = (float*)(ws + (512 << 10));                   // 512 KB
  unsigned short* Qws = (unsigned short*)(ws + (1ull << 20)); // 4 MB  [b][h][l][d]
  unsigned short* Kws = (unsigned short*)(ws + (5ull << 20)); // 32 MB [b][h][t][d]
  unsigned short* Vws = (unsigned short*)(ws + (37ull << 20));// 32 MB [b][h][d][t]
  unsigned short* Ows = (unsigned short*)(ws + (69ull << 20));// 4 MB  [b*l][1024]

  rope_table<<<dim3(512), dim3(256), 0, stream>>>(cost, sint);
  gemm_proj<0, false><<<dim3(16 * 8), dim3(256), 0, stream>>>(latents, Wq, bq, Qws, cost, sint, nullptr);
  gemm_proj<1, false><<<dim3(128 * 8), dim3(256), 0, stream>>>(target, Wk, bk, Kws, cost, sint, ts);
  gemm_proj<2, false><<<dim3(128 * 8), dim3(256), 0, stream>>>(target, Wv, bv, Vws, cost, sint, nullptr);
  attn_kernel<<<dim3(512), dim3(256), 0, stream>>>(Qws, Kws, Vws, mask, Ows);
  gemm_proj<3, true><<<dim3(16 * 8), dim3(256), 0, stream>>>(Ows, Wo, bo, out, nullptr, nullptr, nullptr);
}

// Round 2
// 440.082 us; speedup vs baseline: 1.0583x; 1.0583x over previous
//
#include <hip/hip_runtime.h>

// Problem constants
#define B_ 4
#define L_ 512
#define T_ 4096
#define NH_ 16
#define HD_ 64
// HID = 1024, MAX_POS = 4096

using f32x4 = __attribute__((ext_vector_type(4))) float;
using bf16x8 = __attribute__((ext_vector_type(8))) short;
using u32x4 = __attribute__((ext_vector_type(4))) unsigned int;

__device__ __forceinline__ unsigned short f2bf(float x) {
  unsigned int u = __builtin_bit_cast(unsigned int, x);
  u += 0x7fffu + ((u >> 16) & 1u);
  return (unsigned short)(u >> 16);
}

__device__ __forceinline__ u32x4 cvt8(const float4& a, const float4& b) {
  u32x4 r;
  r[0] = (unsigned)f2bf(a.x) | ((unsigned)f2bf(a.y) << 16);
  r[1] = (unsigned)f2bf(a.z) | ((unsigned)f2bf(a.w) << 16);
  r[2] = (unsigned)f2bf(b.x) | ((unsigned)f2bf(b.y) << 16);
  r[3] = (unsigned)f2bf(b.z) | ((unsigned)f2bf(b.w) << 16);
  return r;
}

__device__ __forceinline__ void gload16(const void* g, void* l) {
  __builtin_amdgcn_global_load_lds(
      (const __attribute__((address_space(1))) unsigned int*)g,
      (__attribute__((address_space(3))) unsigned int*)l, 16, 0, 0);
}

#define BC8(x) __builtin_bit_cast(bf16x8, (x))

// ---------------- f32 -> bf16 bulk convert (6 regions, one pass) ----------------
struct CvtArgs {
  const float* src[6];
  unsigned short* dst[6];
  int cum[7];  // cumulative chunk counts (chunk = 8 elems)
};

__global__ void cvt_bf16(CvtArgs a, int total) {
  for (int g = blockIdx.x * 256 + threadIdx.x; g < total; g += gridDim.x * 256) {
    int r = 0;
#pragma unroll
    for (int q = 0; q < 5; ++q) r += (g >= a.cum[q + 1]);
    const int lc = g - a.cum[r];
    const float4* s = (const float4*)a.src[r] + (size_t)lc * 2;
    float4 x0 = s[0], x1 = s[1];
    *((u32x4*)a.dst[r] + lc) = cvt8(x0, x1);
  }
}

// cos/sin tables: [4096 pos][32] each (emb duplicates freqs, so 32 suffices)
__global__ void rope_table(float* __restrict__ cost, float* __restrict__ sint) {
  const int idx = blockIdx.x * 256 + threadIdx.x;  // 4096*32 total
  const int pos = idx >> 5, i = idx & 31;
  const float inv = 1.0f / powf(10000.0f, (float)(2 * i) * (1.0f / 64.0f));
  const float f = (float)pos * inv;
  cost[idx] = cosf(f);
  sint[idx] = sinf(f);
}

// C = A @ W.T + bias. A,W bf16 [rows][1024]. 128x128 tile, BK=32, 4 waves.
// Double-buffered LDS via global_load_lds w16 (2-phase pipeline, 1 barrier/kt).
// EPI: 0=Q(rope->[b][h][l][d] bf16) 1=K(rope->[b][h][t][d] bf16)
//      2=V(->[b][h][d][t] bf16)     3=out(f32 row-major)
template <int EPI>
__global__ __launch_bounds__(256, 2) void gemm_bf(
    const unsigned short* __restrict__ A, const unsigned short* __restrict__ Wb,
    const float* __restrict__ bias, void* __restrict__ outp,
    const float* __restrict__ cost, const float* __restrict__ sint,
    const int* __restrict__ ts) {
  __shared__ u32x4 lsA[2][512];  // [buf][kg 0..3][row 0..127] chunks of 8 bf16
  __shared__ u32x4 lsB[2][512];
  const int tid = threadIdx.x;
  const int mt = blockIdx.x >> 3, nt = blockIdx.x & 7;
  const int mBase = mt << 7, nBase = nt << 7;
  const int lane = tid & 63, wid = tid >> 6;
  const int wr = wid >> 1, wc = wid & 1;
  const int lr = lane & 15, lg = lane >> 4;

  f32x4 acc[4][4];
#pragma unroll
  for (int m = 0; m < 4; ++m)
#pragma unroll
    for (int n = 0; n < 4; ++n) acc[m][n] = (f32x4){0.f, 0.f, 0.f, 0.f};

  auto stage = [&](int bi, int kt) {
    const int ko = kt * 32;
#pragma unroll
    for (int j2 = 0; j2 < 2; ++j2) {
      const int j = wid * 2 + j2;           // 0..7
      const int row = (j & 1) * 64 + lane;  // chunk j*64+lane = [kg=j>>1][row]
      const int kg = j >> 1;
      gload16(A + (size_t)(mBase + row) * 1024 + ko + kg * 8,
              (unsigned short*)lsA[bi] + j * 512);
      gload16(Wb + (size_t)(nBase + row) * 1024 + ko + kg * 8,
              (unsigned short*)lsB[bi] + j * 512);
    }
  };

  stage(0, 0);
  __syncthreads();
  int cur = 0;
  for (int kt = 0; kt < 32; ++kt) {
    if (kt < 31) stage(cur ^ 1, kt + 1);
    const u32x4* As = lsA[cur];
    const u32x4* Bs = lsB[cur];
    bf16x8 af[4], bfr[4];
#pragma unroll
    for (int m = 0; m < 4; ++m) af[m] = BC8(As[lg * 128 + wr * 64 + m * 16 + lr]);
#pragma unroll
    for (int n = 0; n < 4; ++n) bfr[n] = BC8(Bs[lg * 128 + wc * 64 + n * 16 + lr]);
#pragma unroll
    for (int m = 0; m < 4; ++m)
#pragma unroll
      for (int n = 0; n < 4; ++n)
        acc[m][n] = __builtin_amdgcn_mfma_f32_16x16x32_bf16(af[m], bfr[n], acc[m][n], 0, 0, 0);
    __syncthreads();
    cur ^= 1;
  }

  // ---- epilogue ----
  float bv[4];
#pragma unroll
  for (int n = 0; n < 4; ++n) bv[n] = bias[nBase + wc * 64 + n * 16 + lr];

  if (EPI == 3) {
    float* Of = (float*)outp;
#pragma unroll
    for (int m = 0; m < 4; ++m)
#pragma unroll
      for (int r = 0; r < 4; ++r) {
        const int gR = mBase + wr * 64 + m * 16 + lg * 4 + r;
#pragma unroll
        for (int n = 0; n < 4; ++n)
          Of[(size_t)gR * 1024 + nBase + wc * 64 + n * 16 + lr] = acc[m][n][r] + bv[n];
      }
  } else if (EPI == 2) {
    unsigned short* Vo = (unsigned short*)outp;
    const int h = (nBase >> 6) + wc;
#pragma unroll
    for (int m = 0; m < 4; ++m) {
      const int r0 = mBase + wr * 64 + m * 16 + lg * 4;
      const int b = r0 >> 12, t = r0 & 4095;
#pragma unroll
      for (int n = 0; n < 4; ++n) {
        const int d = n * 16 + lr;
        ushort4 pk;
        pk.x = f2bf(acc[m][n][0] + bv[n]);
        pk.y = f2bf(acc[m][n][1] + bv[n]);
        pk.z = f2bf(acc[m][n][2] + bv[n]);
        pk.w = f2bf(acc[m][n][3] + bv[n]);
        *(ushort4*)(Vo + (((size_t)(b * NH_ + h)) * HD_ + d) * (size_t)T_ + t) = pk;
      }
    }
  } else {
    unsigned short* Qo = (unsigned short*)outp;
    const int h = (nBase >> 6) + wc;
    const int P = (EPI == 0) ? L_ : T_;
#pragma unroll
    for (int m = 0; m < 4; ++m) {
#pragma unroll
      for (int r = 0; r < 4; ++r) {
        const int gR = mBase + wr * 64 + m * 16 + lg * 4 + r;
        int b2, p2, pos;
        if (EPI == 0) {
          b2 = gR >> 9;
          p2 = gR & 511;
          pos = (int)(((float)p2 * 4095.0f) / 511.0f);  // matches jnp f32 mul/div + trunc
        } else {
          b2 = gR >> 12;
          p2 = gR & 4095;
          pos = ts[gR];
        }
        const float* cp = cost + pos * 32;
        const float* sp = sint + pos * 32;
        const size_t obase = (((size_t)(b2 * NH_ + h)) * P + p2) * HD_;
#pragma unroll
        for (int n = 0; n < 2; ++n) {
          const int d = n * 16 + lr;
          const float x1 = acc[m][n][r] + bv[n];
          const float x2 = acc[m][n + 2][r] + bv[n + 2];
          const float c = cp[d], s = sp[d];
          Qo[obase + d] = f2bf(x1 * c - x2 * s);
          Qo[obase + d + 32] = f2bf(x2 * c + x1 * s);
        }
      }
    }
  }
}

// Flash attention v2: XCD-swizzled grid + double-buffered K/V staging.
// Grid 512 blocks (XCD x owns all 8 l-tiles of bh in [x*8, x*8+8)), 4 waves.
// Q: [b][h][l][d] bf16; K: [b][h][t][d] bf16; V: [b][h][d][t] bf16; O: [b*l][1024] bf16.
__global__ __launch_bounds__(256, 2) void attn_v2(
    const unsigned short* __restrict__ Q, const unsigned short* __restrict__ K,
    const unsigned short* __restrict__ V, const int* __restrict__ mask,
    unsigned short* __restrict__ O) {
  __shared__ u32x4 QP[512];     // 8KB: Q chunks [kg 0..7][row 0..63]; per-wave P after
  __shared__ u32x4 Ks[2][512];  // 2x8KB: [kg 0..7][t 0..63]
  __shared__ u32x4 Vs[2][512];  // 2x8KB: [tg 0..7][d 0..63]
  const int tid = threadIdx.x, lane = tid & 63, w = tid >> 6;
  const int lr = lane & 15, lg = lane >> 4;
  const int orig = blockIdx.x;
  const int wg = (orig & 7) * 64 + (orig >> 3);  // bijective XCD swizzle (512 % 8 == 0)
  const int lt = wg & 7, bh = wg >> 3;
  const int b = bh >> 4, h = bh & 15;
  const int l0 = lt << 6;

#pragma unroll
  for (int i = 0; i < 2; ++i) {
    const int li = w * 2 + i;
    gload16(Q + ((size_t)bh * L_ + l0 + lane) * HD_ + li * 8, (unsigned short*)QP + li * 512);
  }
  __syncthreads();
  bf16x8 qf[2];
#pragma unroll
  for (int ks2 = 0; ks2 < 2; ++ks2)
    qf[ks2] = BC8(QP[(ks2 * 4 + lg) * 64 + w * 16 + lr]);
  // qf ds_reads drain at the next barrier (before any wave writes P into QP).

  f32x4 po[4];
#pragma unroll
  for (int n = 0; n < 4; ++n) po[n] = (f32x4){0.f, 0.f, 0.f, 0.f};
  float mrun[4], lrun[4];
#pragma unroll
  for (int r = 0; r < 4; ++r) { mrun[r] = -1e30f; lrun[r] = 0.f; }

  unsigned short* Pw = (unsigned short*)QP + w * 1024;  // 16x64 bf16, XOR-swizzled
  const u32x4* Pr = QP + w * 128;
  const int* mrow = mask + (size_t)b * T_;

  auto stage = [&](int bi, int it) {
    const int t0 = it << 6;
#pragma unroll
    for (int i = 0; i < 2; ++i) {
      const int li = w * 2 + i;
      gload16(K + ((size_t)bh * T_ + t0 + lane) * HD_ + li * 8, (unsigned short*)Ks[bi] + li * 512);
      gload16(V + ((size_t)bh * HD_ + lane) * T_ + t0 + li * 8, (unsigned short*)Vs[bi] + li * 512);
    }
  };

  stage(0, 0);
  __syncthreads();
  int cur = 0;
  for (int it = 0; it < 64; ++it) {
    if (it < 63) stage(cur ^ 1, it + 1);  // prefetch overlaps this iter's compute
    const int t0 = it << 6;

    f32x4 s[4];
#pragma unroll
    for (int n = 0; n < 4; ++n) s[n] = (f32x4){0.f, 0.f, 0.f, 0.f};
#pragma unroll
    for (int ks2 = 0; ks2 < 2; ++ks2) {
#pragma unroll
      for (int n = 0; n < 4; ++n) {
        bf16x8 kb = BC8(Ks[cur][(ks2 * 4 + lg) * 64 + n * 16 + lr]);
        s[n] = __builtin_amdgcn_mfma_f32_16x16x32_bf16(qf[ks2], kb, s[n], 0, 0, 0);
      }
    }
    float mb[4];
#pragma unroll
    for (int n = 0; n < 4; ++n) mb[n] = mrow[t0 + n * 16 + lr] ? 0.f : -1e30f;
#pragma unroll
    for (int n = 0; n < 4; ++n)
#pragma unroll
      for (int r = 0; r < 4; ++r) s[n][r] = s[n][r] * 0.125f + mb[n];
#pragma unroll
    for (int r = 0; r < 4; ++r) {
      float x = fmaxf(fmaxf(s[0][r], s[1][r]), fmaxf(s[2][r], s[3][r]));
      x = fmaxf(x, __shfl_xor(x, 1));
      x = fmaxf(x, __shfl_xor(x, 2));
      x = fmaxf(x, __shfl_xor(x, 4));
      x = fmaxf(x, __shfl_xor(x, 8));
      const float mnew = fmaxf(mrun[r], x);
      const float sc = __expf(mrun[r] - mnew);
      mrun[r] = mnew;
      float rs = 0.f;
#pragma unroll
      for (int n = 0; n < 4; ++n) {
        const float p = __expf(s[n][r] - mnew);
        s[n][r] = p;
        rs += p;
      }
      rs += __shfl_xor(rs, 1);
      rs += __shfl_xor(rs, 2);
      rs += __shfl_xor(rs, 4);
      rs += __shfl_xor(rs, 8);
      lrun[r] = lrun[r] * sc + rs;
#pragma unroll
      for (int n = 0; n < 4; ++n) po[n][r] *= sc;
    }
    // P -> LDS (rows l = lg*4+r, cols t = n*16+lr), granule XOR-swizzle
#pragma unroll
    for (int r = 0; r < 4; ++r) {
      const int l = lg * 4 + r;
      const int lb = l * 64, swz = l & 7;
#pragma unroll
      for (int n = 0; n < 4; ++n) {
        const int t = n * 16 + lr;
        Pw[lb + (((t >> 3) ^ swz) << 3) + (t & 7)] = f2bf(s[n][r]);
      }
    }
    // PV: O += P @ V^T(d-major)
#pragma unroll
    for (int ks2 = 0; ks2 < 2; ++ks2) {
      const int g = ks2 * 4 + lg;
      bf16x8 pa = BC8(Pr[lr * 8 + (g ^ (lr & 7))]);
#pragma unroll
      for (int n = 0; n < 4; ++n) {
        bf16x8 vb = BC8(Vs[cur][g * 64 + n * 16 + lr]);
        po[n] = __builtin_amdgcn_mfma_f32_16x16x32_bf16(pa, vb, po[n], 0, 0, 0);
      }
    }
    __syncthreads();
    cur ^= 1;
  }
#pragma unroll
  for (int r = 0; r < 4; ++r) {
    const float inv = 1.0f / lrun[r];
    const int gl = l0 + w * 16 + lg * 4 + r;
    unsigned short* orow = O + ((size_t)b * L_ + gl) * 1024 + h * HD_;
#pragma unroll
    for (int n = 0; n < 4; ++n) orow[n * 16 + lr] = f2bf(po[n][r] * inv);
  }
}

extern "C" void kernel_launch(void* const* d_in, const int* in_sizes, int n_in,
                              void* d_out, int out_size, void* d_ws, size_t ws_size,
                              hipStream_t stream) {
  const float* latents = (const float*)d_in[0];
  const float* target = (const float*)d_in[1];
  const int* mask = (const int*)d_in[2];
  const int* ts = (const int*)d_in[3];
  const float* Wq = (const float*)d_in[4];
  const float* bq = (const float*)d_in[5];
  const float* Wk = (const float*)d_in[6];
  const float* bk = (const float*)d_in[7];
  const float* Wv = (const float*)d_in[8];
  const float* bv = (const float*)d_in[9];
  const float* Wo = (const float*)d_in[10];
  const float* bo = (const float*)d_in[11];
  float* out = (float*)d_out;

  // ws layout (117 MB total):
  char* ws = (char*)d_ws;
  float* cost = (float*)ws;                                    // 512 KB
  float* sint = (float*)(ws + (512 << 10));                    // 512 KB
  unsigned short* Qws = (unsigned short*)(ws + (1ull << 20));  // 4 MB  [b][h][l][d]
  unsigned short* Kws = (unsigned short*)(ws + (5ull << 20));  // 32 MB [b][h][t][d]
  unsigned short* Vws = (unsigned short*)(ws + (37ull << 20)); // 32 MB [b][h][d][t]
  unsigned short* Ows = (unsigned short*)(ws + (69ull << 20)); // 4 MB  [b*l][1024]
  unsigned short* latb = (unsigned short*)(ws + (73ull << 20));// 4 MB
  unsigned short* tgtb = (unsigned short*)(ws + (77ull << 20));// 32 MB
  unsigned short* Wqb = (unsigned short*)(ws + (109ull << 20));// 2 MB
  unsigned short* Wkb = (unsigned short*)(ws + (111ull << 20));// 2 MB
  unsigned short* Wvb = (unsigned short*)(ws + (113ull << 20));// 2 MB
  unsigned short* Wob = (unsigned short*)(ws + (115ull << 20));// 2 MB

  CvtArgs ca;
  ca.src[0] = latents; ca.dst[0] = latb;
  ca.src[1] = target;  ca.dst[1] = tgtb;
  ca.src[2] = Wq;      ca.dst[2] = Wqb;
  ca.src[3] = Wk;      ca.dst[3] = Wkb;
  ca.src[4] = Wv;      ca.dst[4] = Wvb;
  ca.src[5] = Wo;      ca.dst[5] = Wob;
  const int nch[6] = {2097152 / 8, 16777216 / 8, 131072, 131072, 131072, 131072};
  ca.cum[0] = 0;
  for (int i = 0; i < 6; ++i) ca.cum[i + 1] = ca.cum[i] + nch[i];
  const int total = ca.cum[6];

  cvt_bf16<<<dim3(2048), dim3(256), 0, stream>>>(ca, total);
  rope_table<<<dim3(512), dim3(256), 0, stream>>>(cost, sint);
  gemm_bf<0><<<dim3(16 * 8), dim3(256), 0, stream>>>(latb, Wqb, bq, Qws, cost, sint, nullptr);
  gemm_bf<1><<<dim3(128 * 8), dim3(256), 0, stream>>>(tgtb, Wkb, bk, Kws, cost, sint, ts);
  gemm_bf<2><<<dim3(128 * 8), dim3(256), 0, stream>>>(tgtb, Wvb, bv, Vws, nullptr, nullptr, nullptr);
  attn_v2<<<dim3(512), dim3(256), 0, stream>>>(Qws, Kws, Vws, mask, Ows);
  gemm_bf<3><<<dim3(16 * 8), dim3(256), 0, stream>>>(Ows, Wob, bo, out, nullptr, nullptr, nullptr);
}

// Round 3
// 366.740 us; speedup vs baseline: 1.2699x; 1.2000x over previous
//
#include <hip/hip_runtime.h>

// Problem constants
#define B_ 4
#define L_ 512
#define T_ 4096
#define NH_ 16
#define HD_ 64
// HID = 1024, MAX_POS = 4096

using f32x4 = __attribute__((ext_vector_type(4))) float;
using bf16x8 = __attribute__((ext_vector_type(8))) short;
using u32x4 = __attribute__((ext_vector_type(4))) unsigned int;

__device__ __forceinline__ unsigned short f2bf(float x) {
  unsigned int u = __builtin_bit_cast(unsigned int, x);
  u += 0x7fffu + ((u >> 16) & 1u);
  return (unsigned short)(u >> 16);
}

__device__ __forceinline__ u32x4 cvt8(const float4& a, const float4& b) {
  u32x4 r;
  r[0] = (unsigned)f2bf(a.x) | ((unsigned)f2bf(a.y) << 16);
  r[1] = (unsigned)f2bf(a.z) | ((unsigned)f2bf(a.w) << 16);
  r[2] = (unsigned)f2bf(b.x) | ((unsigned)f2bf(b.y) << 16);
  r[3] = (unsigned)f2bf(b.z) | ((unsigned)f2bf(b.w) << 16);
  return r;
}

__device__ __forceinline__ void gload16(const void* g, void* l) {
  __builtin_amdgcn_global_load_lds(
      (const __attribute__((address_space(1))) unsigned int*)g,
      (__attribute__((address_space(3))) unsigned int*)l, 16, 0, 0);
}

#define BC8(x) __builtin_bit_cast(bf16x8, (x))

// ---------------- f32 -> bf16 bulk convert (6 regions, one pass) ----------------
struct CvtArgs {
  const float* src[6];
  unsigned short* dst[6];
  int cum[7];  // cumulative chunk counts (chunk = 8 elems)
};

__global__ void cvt_bf16(CvtArgs a, int total) {
  for (int g = blockIdx.x * 256 + threadIdx.x; g < total; g += gridDim.x * 256) {
    int r = 0;
#pragma unroll
    for (int q = 0; q < 5; ++q) r += (g >= a.cum[q + 1]);
    const int lc = g - a.cum[r];
    const float4* s = (const float4*)a.src[r] + (size_t)lc * 2;
    float4 x0 = s[0], x1 = s[1];
    *((u32x4*)a.dst[r] + lc) = cvt8(x0, x1);
  }
}

// cos/sin tables [4096 pos][32] each + mask -> float bias (0 / -1e30)
__global__ void rope_table(float* __restrict__ cost, float* __restrict__ sint,
                           const int* __restrict__ mask, float* __restrict__ mbias) {
  const int idx = blockIdx.x * 256 + threadIdx.x;  // 4096*32 total
  const int pos = idx >> 5, i = idx & 31;
  const float inv = 1.0f / powf(10000.0f, (float)(2 * i) * (1.0f / 64.0f));
  const float f = (float)pos * inv;
  cost[idx] = cosf(f);
  sint[idx] = sinf(f);
  if (idx < B_ * T_) mbias[idx] = mask[idx] ? 0.f : -1e30f;
}

// C = A @ W.T + bias. A,W bf16 [rows][1024]. 128x128 tile, BK=32, 4 waves.
// Double-buffered LDS via global_load_lds w16 (2-phase pipeline, 1 barrier/kt).
// EPI: 0=Q(rope->[b][h][l][d] bf16) 1=K(rope->[b][h][t][d] bf16)
//      2=V(->[b][h][d][t] bf16)     3=out(f32 row-major)
template <int EPI>
__global__ __launch_bounds__(256, 2) void gemm_bf(
    const unsigned short* __restrict__ A, const unsigned short* __restrict__ Wb,
    const float* __restrict__ bias, void* __restrict__ outp,
    const float* __restrict__ cost, const float* __restrict__ sint,
    const int* __restrict__ ts) {
  __shared__ u32x4 lsA[2][512];  // [buf][kg 0..3][row 0..127] chunks of 8 bf16
  __shared__ u32x4 lsB[2][512];
  const int tid = threadIdx.x;
  const int mt = blockIdx.x >> 3, nt = blockIdx.x & 7;
  const int mBase = mt << 7, nBase = nt << 7;
  const int lane = tid & 63, wid = tid >> 6;
  const int wr = wid >> 1, wc = wid & 1;
  const int lr = lane & 15, lg = lane >> 4;

  f32x4 acc[4][4];
#pragma unroll
  for (int m = 0; m < 4; ++m)
#pragma unroll
    for (int n = 0; n < 4; ++n) acc[m][n] = (f32x4){0.f, 0.f, 0.f, 0.f};

  auto stage = [&](int bi, int kt) {
    const int ko = kt * 32;
#pragma unroll
    for (int j2 = 0; j2 < 2; ++j2) {
      const int j = wid * 2 + j2;           // 0..7
      const int row = (j & 1) * 64 + lane;  // chunk j*64+lane = [kg=j>>1][row]
      const int kg = j >> 1;
      gload16(A + (size_t)(mBase + row) * 1024 + ko + kg * 8,
              (unsigned short*)lsA[bi] + j * 512);
      gload16(Wb + (size_t)(nBase + row) * 1024 + ko + kg * 8,
              (unsigned short*)lsB[bi] + j * 512);
    }
  };

  stage(0, 0);
  __syncthreads();
  int cur = 0;
  for (int kt = 0; kt < 32; ++kt) {
    if (kt < 31) stage(cur ^ 1, kt + 1);
    const u32x4* As = lsA[cur];
    const u32x4* Bs = lsB[cur];
    bf16x8 af[4], bfr[4];
#pragma unroll
    for (int m = 0; m < 4; ++m) af[m] = BC8(As[lg * 128 + wr * 64 + m * 16 + lr]);
#pragma unroll
    for (int n = 0; n < 4; ++n) bfr[n] = BC8(Bs[lg * 128 + wc * 64 + n * 16 + lr]);
#pragma unroll
    for (int m = 0; m < 4; ++m)
#pragma unroll
      for (int n = 0; n < 4; ++n)
        acc[m][n] = __builtin_amdgcn_mfma_f32_16x16x32_bf16(af[m], bfr[n], acc[m][n], 0, 0, 0);
    __syncthreads();
    cur ^= 1;
  }

  // ---- epilogue ----
  float bv[4];
#pragma unroll
  for (int n = 0; n < 4; ++n) bv[n] = bias[nBase + wc * 64 + n * 16 + lr];

  if (EPI == 3) {
    float* Of = (float*)outp;
#pragma unroll
    for (int m = 0; m < 4; ++m)
#pragma unroll
      for (int r = 0; r < 4; ++r) {
        const int gR = mBase + wr * 64 + m * 16 + lg * 4 + r;
#pragma unroll
        for (int n = 0; n < 4; ++n)
          Of[(size_t)gR * 1024 + nBase + wc * 64 + n * 16 + lr] = acc[m][n][r] + bv[n];
      }
  } else if (EPI == 2) {
    unsigned short* Vo = (unsigned short*)outp;
    const int h = (nBase >> 6) + wc;
#pragma unroll
    for (int m = 0; m < 4; ++m) {
      const int r0 = mBase + wr * 64 + m * 16 + lg * 4;
      const int b = r0 >> 12, t = r0 & 4095;
#pragma unroll
      for (int n = 0; n < 4; ++n) {
        const int d = n * 16 + lr;
        ushort4 pk;
        pk.x = f2bf(acc[m][n][0] + bv[n]);
        pk.y = f2bf(acc[m][n][1] + bv[n]);
        pk.z = f2bf(acc[m][n][2] + bv[n]);
        pk.w = f2bf(acc[m][n][3] + bv[n]);
        *(ushort4*)(Vo + (((size_t)(b * NH_ + h)) * HD_ + d) * (size_t)T_ + t) = pk;
      }
    }
  } else {
    unsigned short* Qo = (unsigned short*)outp;
    const int h = (nBase >> 6) + wc;
    const int P = (EPI == 0) ? L_ : T_;
#pragma unroll
    for (int m = 0; m < 4; ++m) {
#pragma unroll
      for (int r = 0; r < 4; ++r) {
        const int gR = mBase + wr * 64 + m * 16 + lg * 4 + r;
        int b2, p2, pos;
        if (EPI == 0) {
          b2 = gR >> 9;
          p2 = gR & 511;
          pos = (int)(((float)p2 * 4095.0f) / 511.0f);  // matches jnp f32 mul/div + trunc
        } else {
          b2 = gR >> 12;
          p2 = gR & 4095;
          pos = ts[gR];
        }
        const float* cp = cost + pos * 32;
        const float* sp = sint + pos * 32;
        const size_t obase = (((size_t)(b2 * NH_ + h)) * P + p2) * HD_;
#pragma unroll
        for (int n = 0; n < 2; ++n) {
          const int d = n * 16 + lr;
          const float x1 = acc[m][n][r] + bv[n];
          const float x2 = acc[m][n + 2][r] + bv[n + 2];
          const float c = cp[d], s = sp[d];
          Qo[obase + d] = f2bf(x1 * c - x2 * s);
          Qo[obase + d + 32] = f2bf(x2 * c + x1 * s);
        }
      }
    }
  }
}

// Flash attention, T-split x2 (flash-decoding). Grid 1024 blocks:
// (bh, lt, half), XCD-swizzled so one bh's 16 blocks share an XCD. 4 waves.
// Softmax in exp2 domain; deferred l-reduce; partials (po,m,l) -> ws.
#define SCL 0.180336880111f  // 0.125 * log2(e)
__global__ __launch_bounds__(256, 4) void attn_half(
    const unsigned short* __restrict__ Q, const unsigned short* __restrict__ K,
    const unsigned short* __restrict__ V, const float* __restrict__ mbias,
    float* __restrict__ pws, float* __restrict__ mlws) {
  __shared__ u32x4 QP[512];     // 8KB: Q chunks; per-wave P after
  __shared__ u32x4 Ks[2][512];  // 2x8KB: [kg 0..7][t 0..63]
  __shared__ u32x4 Vs[2][512];  // 2x8KB: [tg 0..7][d 0..63]
  const int tid = threadIdx.x, lane = tid & 63, w = tid >> 6;
  const int lr = lane & 15, lg = lane >> 4;
  const int orig = blockIdx.x;
  const int wg = (orig & 7) * 128 + (orig >> 3);  // bijective (1024 % 8 == 0)
  const int half = wg & 1, lt = (wg >> 1) & 7, bh = wg >> 4;
  const int b = bh >> 4, h = bh & 15;
  const int l0 = lt << 6;
  const int tBase = half << 11;  // 2048

#pragma unroll
  for (int i = 0; i < 2; ++i) {
    const int li = w * 2 + i;
    gload16(Q + ((size_t)bh * L_ + l0 + lane) * HD_ + li * 8, (unsigned short*)QP + li * 512);
  }
  __syncthreads();
  bf16x8 qf[2];
#pragma unroll
  for (int ks2 = 0; ks2 < 2; ++ks2)
    qf[ks2] = BC8(QP[(ks2 * 4 + lg) * 64 + w * 16 + lr]);
  // qf ds_reads drain at the next barrier (before any wave writes P into QP).

  f32x4 po[4];
#pragma unroll
  for (int n = 0; n < 4; ++n) po[n] = (f32x4){0.f, 0.f, 0.f, 0.f};
  float mrun[4], lrun[4];
#pragma unroll
  for (int r = 0; r < 4; ++r) { mrun[r] = -1e30f; lrun[r] = 0.f; }

  unsigned short* Pw = (unsigned short*)QP + w * 1024;  // 16x64 bf16, XOR-swizzled
  const u32x4* Pr = QP + w * 128;
  const float* mrow = mbias + (size_t)b * T_ + tBase;

  auto stage = [&](int bi, int it) {
    const int t0 = tBase + (it << 6);
#pragma unroll
    for (int i = 0; i < 2; ++i) {
      const int li = w * 2 + i;
      gload16(K + ((size_t)bh * T_ + t0 + lane) * HD_ + li * 8, (unsigned short*)Ks[bi] + li * 512);
      gload16(V + ((size_t)bh * HD_ + lane) * T_ + t0 + li * 8, (unsigned short*)Vs[bi] + li * 512);
    }
  };

  stage(0, 0);
  __syncthreads();
  int cur = 0;
  for (int it = 0; it < 32; ++it) {
    if (it < 31) stage(cur ^ 1, it + 1);  // prefetch overlaps this iter's compute
    const int t0l = it << 6;

    f32x4 s[4];
#pragma unroll
    for (int n = 0; n < 4; ++n) s[n] = (f32x4){0.f, 0.f, 0.f, 0.f};
#pragma unroll
    for (int ks2 = 0; ks2 < 2; ++ks2) {
#pragma unroll
      for (int n = 0; n < 4; ++n) {
        bf16x8 kb = BC8(Ks[cur][(ks2 * 4 + lg) * 64 + n * 16 + lr]);
        s[n] = __builtin_amdgcn_mfma_f32_16x16x32_bf16(qf[ks2], kb, s[n], 0, 0, 0);
      }
    }
    float mb[4];
#pragma unroll
    for (int n = 0; n < 4; ++n) mb[n] = mrow[t0l + n * 16 + lr];
#pragma unroll
    for (int n = 0; n < 4; ++n)
#pragma unroll
      for (int r = 0; r < 4; ++r) s[n][r] = s[n][r] * SCL + mb[n];  // log2-domain
#pragma unroll
    for (int r = 0; r < 4; ++r) {
      float x = fmaxf(fmaxf(s[0][r], s[1][r]), fmaxf(s[2][r], s[3][r]));
      x = fmaxf(x, __shfl_xor(x, 1));
      x = fmaxf(x, __shfl_xor(x, 2));
      x = fmaxf(x, __shfl_xor(x, 4));
      x = fmaxf(x, __shfl_xor(x, 8));
      const float mnew = fmaxf(mrun[r], x);
      const float sc = __builtin_exp2f(mrun[r] - mnew);
      mrun[r] = mnew;
      float lsum = 0.f;
#pragma unroll
      for (int n = 0; n < 4; ++n) {
        const float p = __builtin_exp2f(s[n][r] - mnew);
        s[n][r] = p;
        lsum += p;
      }
      lrun[r] = lrun[r] * sc + lsum;  // per-lane partial; reduced after loop
#pragma unroll
      for (int n = 0; n < 4; ++n) po[n][r] *= sc;
    }
    // P -> LDS (rows l = lg*4+r, cols t = n*16+lr), granule XOR-swizzle
#pragma unroll
    for (int r = 0; r < 4; ++r) {
      const int l = lg * 4 + r;
      const int lb = l * 64, swz = l & 7;
#pragma unroll
      for (int n = 0; n < 4; ++n) {
        const int t = n * 16 + lr;
        Pw[lb + (((t >> 3) ^ swz) << 3) + (t & 7)] = f2bf(s[n][r]);
      }
    }
    // PV: O += P @ V^T(d-major)
#pragma unroll
    for (int ks2 = 0; ks2 < 2; ++ks2) {
      const int g = ks2 * 4 + lg;
      bf16x8 pa = BC8(Pr[lr * 8 + (g ^ (lr & 7))]);
#pragma unroll
      for (int n = 0; n < 4; ++n) {
        bf16x8 vb = BC8(Vs[cur][g * 64 + n * 16 + lr]);
        po[n] = __builtin_amdgcn_mfma_f32_16x16x32_bf16(pa, vb, po[n], 0, 0, 0);
      }
    }
    __syncthreads();
    cur ^= 1;
  }

  // deferred l-reduce (group-uniform afterwards), then write partials
  float* pbase = pws + ((size_t)(((bh << 3) + lt) * 2 + half)) * 4096;
  float* mlbase = mlws + ((size_t)(((bh << 3) + lt) * 2 + half)) * 128;
#pragma unroll
  for (int r = 0; r < 4; ++r) {
    float rs = lrun[r];
    rs += __shfl_xor(rs, 1);
    rs += __shfl_xor(rs, 2);
    rs += __shfl_xor(rs, 4);
    rs += __shfl_xor(rs, 8);
    lrun[r] = rs;
    const int l = w * 16 + lg * 4 + r;
#pragma unroll
    for (int n = 0; n < 4; ++n) pbase[l * 64 + n * 16 + lr] = po[n][r];
    if (lr == 0) {
      mlbase[l * 2] = mrun[r];
      mlbase[l * 2 + 1] = lrun[r];
    }
  }
}

// Combine the two T-halves. Grid 512 = (bh, lt), 256 thr.
__global__ void attn_combine(const float* __restrict__ pws, const float* __restrict__ mlws,
                             unsigned short* __restrict__ O) {
  const int blk = blockIdx.x;
  const int bh = blk >> 3, lt = blk & 7;
  const int b = bh >> 4, h = bh & 15;
  const int tid = threadIdx.x;
  const int row = tid >> 2, seg = tid & 3;  // 16 d's per thread
  const float* p0 = pws + ((size_t)blk * 2) * 4096 + row * 64 + seg * 16;
  const float* p1 = p0 + 4096;
  const float* ml0 = mlws + ((size_t)blk * 2) * 128 + row * 2;
  const float* ml1 = ml0 + 128;
  const float m0 = ml0[0], li0 = ml0[1], m1 = ml1[0], li1 = ml1[1];
  const float M = fmaxf(m0, m1);
  const float w0 = __builtin_exp2f(m0 - M), w1 = __builtin_exp2f(m1 - M);
  const float inv = 1.0f / (li0 * w0 + li1 * w1);
  const int gl = lt * 64 + row;
  unsigned short* orow = O + ((size_t)b * L_ + gl) * 1024 + h * HD_ + seg * 16;
#pragma unroll
  for (int j = 0; j < 4; ++j) {
    const float4 a = *(const float4*)(p0 + j * 4);
    const float4 c = *(const float4*)(p1 + j * 4);
    ushort4 pk;
    pk.x = f2bf((a.x * w0 + c.x * w1) * inv);
    pk.y = f2bf((a.y * w0 + c.y * w1) * inv);
    pk.z = f2bf((a.z * w0 + c.z * w1) * inv);
    pk.w = f2bf((a.w * w0 + c.w * w1) * inv);
    *(ushort4*)(orow + j * 4) = pk;
  }
}

extern "C" void kernel_launch(void* const* d_in, const int* in_sizes, int n_in,
                              void* d_out, int out_size, void* d_ws, size_t ws_size,
                              hipStream_t stream) {
  const float* latents = (const float*)d_in[0];
  const float* target = (const float*)d_in[1];
  const int* mask = (const int*)d_in[2];
  const int* ts = (const int*)d_in[3];
  const float* Wq = (const float*)d_in[4];
  const float* bq = (const float*)d_in[5];
  const float* Wk = (const float*)d_in[6];
  const float* bk = (const float*)d_in[7];
  const float* Wv = (const float*)d_in[8];
  const float* bv = (const float*)d_in[9];
  const float* Wo = (const float*)d_in[10];
  const float* bo = (const float*)d_in[11];
  float* out = (float*)d_out;

  // ws layout (117 MB total):
  char* ws = (char*)d_ws;
  float* cost = (float*)ws;                                    // 512 KB
  float* sint = (float*)(ws + (512 << 10));                    // 512 KB
  unsigned short* Qws = (unsigned short*)(ws + (1ull << 20));  // 4 MB  [b][h][l][d]
  unsigned short* Kws = (unsigned short*)(ws + (5ull << 20));  // 32 MB [b][h][t][d]
  unsigned short* Vws = (unsigned short*)(ws + (37ull << 20)); // 32 MB [b][h][d][t]
  // mbias overlays Ows head: written pre-GEMM, read by attn_half, dead before combine writes Ows
  float* mbias = (float*)(ws + (69ull << 20));                 // 64 KB
  unsigned short* Ows = (unsigned short*)(ws + (69ull << 20)); // 4 MB  [b*l][1024]
  unsigned short* latb = (unsigned short*)(ws + (73ull << 20));// 4 MB
  unsigned short* tgtb = (unsigned short*)(ws + (77ull << 20));// 32 MB (dead after gemm<2>)
  float* pws = (float*)(ws + (77ull << 20));                   // 16 MB (overlays tgtb)
  float* mlws = (float*)(ws + (93ull << 20));                  // 512 KB
  unsigned short* Wqb = (unsigned short*)(ws + (109ull << 20));// 2 MB
  unsigned short* Wkb = (unsigned short*)(ws + (111ull << 20));// 2 MB
  unsigned short* Wvb = (unsigned short*)(ws + (113ull << 20));// 2 MB
  unsigned short* Wob = (unsigned short*)(ws + (115ull << 20));// 2 MB

  CvtArgs ca;
  ca.src[0] = latents; ca.dst[0] = latb;
  ca.src[1] = target;  ca.dst[1] = tgtb;
  ca.src[2] = Wq;      ca.dst[2] = Wqb;
  ca.src[3] = Wk;      ca.dst[3] = Wkb;
  ca.src[4] = Wv;      ca.dst[4] = Wvb;
  ca.src[5] = Wo;      ca.dst[5] = Wob;
  const int nch[6] = {2097152 / 8, 16777216 / 8, 131072, 131072, 131072, 131072};
  ca.cum[0] = 0;
  for (int i = 0; i < 6; ++i) ca.cum[i + 1] = ca.cum[i] + nch[i];
  const int total = ca.cum[6];

  cvt_bf16<<<dim3(2048), dim3(256), 0, stream>>>(ca, total);
  rope_table<<<dim3(512), dim3(256), 0, stream>>>(cost, sint, mask, mbias);
  gemm_bf<0><<<dim3(16 * 8), dim3(256), 0, stream>>>(latb, Wqb, bq, Qws, cost, sint, nullptr);
  gemm_bf<1><<<dim3(128 * 8), dim3(256), 0, stream>>>(tgtb, Wkb, bk, Kws, cost, sint, ts);
  gemm_bf<2><<<dim3(128 * 8), dim3(256), 0, stream>>>(tgtb, Wvb, bv, Vws, nullptr, nullptr, nullptr);
  attn_half<<<dim3(1024), dim3(256), 0, stream>>>(Qws, Kws, Vws, mbias, pws, mlws);
  attn_combine<<<dim3(512), dim3(256), 0, stream>>>(pws, mlws, Ows);
  gemm_bf<3><<<dim3(16 * 8), dim3(256), 0, stream>>>(Ows, Wob, bo, out, nullptr, nullptr, nullptr);
}

// Round 4
// 317.525 us; speedup vs baseline: 1.4668x; 1.1550x over previous
//
#include <hip/hip_runtime.h>

// Problem constants
#define B_ 4
#define L_ 512
#define T_ 4096
#define NH_ 16
#define HD_ 64
// HID = 1024, MAX_POS = 4096

using f32x4 = __attribute__((ext_vector_type(4))) float;
using bf16x8 = __attribute__((ext_vector_type(8))) short;
using u32x4 = __attribute__((ext_vector_type(4))) unsigned int;

__device__ __forceinline__ unsigned short f2bf(float x) {
  unsigned int u = __builtin_bit_cast(unsigned int, x);
  u += 0x7fffu + ((u >> 16) & 1u);
  return (unsigned short)(u >> 16);
}

__device__ __forceinline__ unsigned cvtpk(float lo, float hi) {
  unsigned r;
  asm("v_cvt_pk_bf16_f32 %0, %1, %2" : "=v"(r) : "v"(lo), "v"(hi));
  return r;
}

__device__ __forceinline__ u32x4 cvt8(const float4& a, const float4& b) {
  u32x4 r;
  r[0] = (unsigned)f2bf(a.x) | ((unsigned)f2bf(a.y) << 16);
  r[1] = (unsigned)f2bf(a.z) | ((unsigned)f2bf(a.w) << 16);
  r[2] = (unsigned)f2bf(b.x) | ((unsigned)f2bf(b.y) << 16);
  r[3] = (unsigned)f2bf(b.z) | ((unsigned)f2bf(b.w) << 16);
  return r;
}

__device__ __forceinline__ void gload16(const void* g, void* l) {
  __builtin_amdgcn_global_load_lds(
      (const __attribute__((address_space(1))) unsigned int*)g,
      (__attribute__((address_space(3))) unsigned int*)l, 16, 0, 0);
}

#define BC8(x) __builtin_bit_cast(bf16x8, (x))

// ---------------- f32 -> bf16 bulk convert (6 regions, one pass) ----------------
struct CvtArgs {
  const float* src[6];
  unsigned short* dst[6];
  int cum[7];  // cumulative chunk counts (chunk = 8 elems)
};

__global__ void cvt_bf16(CvtArgs a, int total) {
  for (int g = blockIdx.x * 256 + threadIdx.x; g < total; g += gridDim.x * 256) {
    int r = 0;
#pragma unroll
    for (int q = 0; q < 5; ++q) r += (g >= a.cum[q + 1]);
    const int lc = g - a.cum[r];
    const float4* s = (const float4*)a.src[r] + (size_t)lc * 2;
    float4 x0 = s[0], x1 = s[1];
    *((u32x4*)a.dst[r] + lc) = cvt8(x0, x1);
  }
}

// cos/sin tables [4096 pos][32] each + mask -> float bias (0 / -1e30)
__global__ void rope_table(float* __restrict__ cost, float* __restrict__ sint,
                           const int* __restrict__ mask, float* __restrict__ mbias) {
  const int idx = blockIdx.x * 256 + threadIdx.x;  // 4096*32 total
  const int pos = idx >> 5, i = idx & 31;
  const float inv = 1.0f / powf(10000.0f, (float)(2 * i) * (1.0f / 64.0f));
  const float f = (float)pos * inv;
  cost[idx] = cosf(f);
  sint[idx] = sinf(f);
  if (idx < B_ * T_) mbias[idx] = mask[idx] ? 0.f : -1e30f;
}

// C = A @ W.T + bias. A,W bf16 [rows][1024]. 128x128 tile, BK=32, 4 waves.
// EPI: 0=Q(rope->[b][h][l][d] bf16)  3=out(f32 row-major)
template <int EPI>
__global__ __launch_bounds__(256, 2) void gemm_bf(
    const unsigned short* __restrict__ A, const unsigned short* __restrict__ Wb,
    const float* __restrict__ bias, void* __restrict__ outp,
    const float* __restrict__ cost, const float* __restrict__ sint,
    const int* __restrict__ ts) {
  __shared__ u32x4 lsA[2][512];  // [buf][kg 0..3][row 0..127] chunks of 8 bf16
  __shared__ u32x4 lsB[2][512];
  const int tid = threadIdx.x;
  const int mt = blockIdx.x >> 3, nt = blockIdx.x & 7;
  const int mBase = mt << 7, nBase = nt << 7;
  const int lane = tid & 63, wid = tid >> 6;
  const int wr = wid >> 1, wc = wid & 1;
  const int lr = lane & 15, lg = lane >> 4;

  f32x4 acc[4][4];
#pragma unroll
  for (int m = 0; m < 4; ++m)
#pragma unroll
    for (int n = 0; n < 4; ++n) acc[m][n] = (f32x4){0.f, 0.f, 0.f, 0.f};

  auto stage = [&](int bi, int kt) {
    const int ko = kt * 32;
#pragma unroll
    for (int j2 = 0; j2 < 2; ++j2) {
      const int j = wid * 2 + j2;           // 0..7
      const int row = (j & 1) * 64 + lane;  // chunk j*64+lane = [kg=j>>1][row]
      const int kg = j >> 1;
      gload16(A + (size_t)(mBase + row) * 1024 + ko + kg * 8,
              (unsigned short*)lsA[bi] + j * 512);
      gload16(Wb + (size_t)(nBase + row) * 1024 + ko + kg * 8,
              (unsigned short*)lsB[bi] + j * 512);
    }
  };

  stage(0, 0);
  __syncthreads();
  int cur = 0;
  for (int kt = 0; kt < 32; ++kt) {
    if (kt < 31) stage(cur ^ 1, kt + 1);
    const u32x4* As = lsA[cur];
    const u32x4* Bs = lsB[cur];
    bf16x8 af[4], bfr[4];
#pragma unroll
    for (int m = 0; m < 4; ++m) af[m] = BC8(As[lg * 128 + wr * 64 + m * 16 + lr]);
#pragma unroll
    for (int n = 0; n < 4; ++n) bfr[n] = BC8(Bs[lg * 128 + wc * 64 + n * 16 + lr]);
#pragma unroll
    for (int m = 0; m < 4; ++m)
#pragma unroll
      for (int n = 0; n < 4; ++n)
        acc[m][n] = __builtin_amdgcn_mfma_f32_16x16x32_bf16(af[m], bfr[n], acc[m][n], 0, 0, 0);
    __syncthreads();
    cur ^= 1;
  }

  float bv[4];
#pragma unroll
  for (int n = 0; n < 4; ++n) bv[n] = bias[nBase + wc * 64 + n * 16 + lr];

  if (EPI == 3) {
    float* Of = (float*)outp;
#pragma unroll
    for (int m = 0; m < 4; ++m)
#pragma unroll
      for (int r = 0; r < 4; ++r) {
        const int gR = mBase + wr * 64 + m * 16 + lg * 4 + r;
#pragma unroll
        for (int n = 0; n < 4; ++n)
          Of[(size_t)gR * 1024 + nBase + wc * 64 + n * 16 + lr] = acc[m][n][r] + bv[n];
      }
  } else {
    unsigned short* Qo = (unsigned short*)outp;
    const int h = (nBase >> 6) + wc;
#pragma unroll
    for (int m = 0; m < 4; ++m) {
#pragma unroll
      for (int r = 0; r < 4; ++r) {
        const int gR = mBase + wr * 64 + m * 16 + lg * 4 + r;
        const int b2 = gR >> 9, p2 = gR & 511;
        const int pos = (int)(((float)p2 * 4095.0f) / 511.0f);  // matches jnp trunc
        const float* cp = cost + pos * 32;
        const float* sp = sint + pos * 32;
        const size_t obase = (((size_t)(b2 * NH_ + h)) * L_ + p2) * HD_;
#pragma unroll
        for (int n = 0; n < 2; ++n) {
          const int d = n * 16 + lr;
          const float x1 = acc[m][n][r] + bv[n];
          const float x2 = acc[m][n + 2][r] + bv[n + 2];
          const float c = cp[d], s = sp[d];
          Qo[obase + d] = f2bf(x1 * c - x2 * s);
          Qo[obase + d + 32] = f2bf(x2 * c + x1 * s);
        }
      }
    }
  }
}

// Fused K+V projection: stage A once, multiply against Wk and Wv.
// K out: rope -> [b][h][t][d] bf16;  V out: [b][h][d][t] bf16.
__global__ __launch_bounds__(256, 2) void gemm_kv(
    const unsigned short* __restrict__ A, const unsigned short* __restrict__ Wkb,
    const unsigned short* __restrict__ Wvb, const float* __restrict__ bkp,
    const float* __restrict__ bvp, unsigned short* __restrict__ Ko,
    unsigned short* __restrict__ Vo, const float* __restrict__ cost,
    const float* __restrict__ sint, const int* __restrict__ ts) {
  __shared__ u32x4 lsA[2][512];
  __shared__ u32x4 lsK[2][512];
  __shared__ u32x4 lsV[2][512];
  const int tid = threadIdx.x;
  const int orig = blockIdx.x;
  const int wgid = (orig & 7) * 128 + (orig >> 3);  // bijective (1024 % 8 == 0)
  const int mt = wgid >> 3, nt = wgid & 7;
  const int mBase = mt << 7, nBase = nt << 7;
  const int lane = tid & 63, wid = tid >> 6;
  const int wr = wid >> 1, wc = wid & 1;
  const int lr = lane & 15, lg = lane >> 4;

  f32x4 accK[4][4], accV[4][4];
#pragma unroll
  for (int m = 0; m < 4; ++m)
#pragma unroll
    for (int n = 0; n < 4; ++n) {
      accK[m][n] = (f32x4){0.f, 0.f, 0.f, 0.f};
      accV[m][n] = (f32x4){0.f, 0.f, 0.f, 0.f};
    }

  auto stage = [&](int bi, int kt) {
    const int ko = kt * 32;
#pragma unroll
    for (int j2 = 0; j2 < 2; ++j2) {
      const int j = wid * 2 + j2;
      const int row = (j & 1) * 64 + lane;
      const int kg = j >> 1;
      gload16(A + (size_t)(mBase + row) * 1024 + ko + kg * 8,
              (unsigned short*)lsA[bi] + j * 512);
      gload16(Wkb + (size_t)(nBase + row) * 1024 + ko + kg * 8,
              (unsigned short*)lsK[bi] + j * 512);
      gload16(Wvb + (size_t)(nBase + row) * 1024 + ko + kg * 8,
              (unsigned short*)lsV[bi] + j * 512);
    }
  };

  stage(0, 0);
  __syncthreads();
  int cur = 0;
  for (int kt = 0; kt < 32; ++kt) {
    if (kt < 31) stage(cur ^ 1, kt + 1);
    const u32x4* As = lsA[cur];
    const u32x4* Ks = lsK[cur];
    const u32x4* Vs = lsV[cur];
    bf16x8 af[4], kf[4], vf[4];
#pragma unroll
    for (int m = 0; m < 4; ++m) af[m] = BC8(As[lg * 128 + wr * 64 + m * 16 + lr]);
#pragma unroll
    for (int n = 0; n < 4; ++n) kf[n] = BC8(Ks[lg * 128 + wc * 64 + n * 16 + lr]);
#pragma unroll
    for (int n = 0; n < 4; ++n) vf[n] = BC8(Vs[lg * 128 + wc * 64 + n * 16 + lr]);
#pragma unroll
    for (int m = 0; m < 4; ++m)
#pragma unroll
      for (int n = 0; n < 4; ++n) {
        accK[m][n] = __builtin_amdgcn_mfma_f32_16x16x32_bf16(af[m], kf[n], accK[m][n], 0, 0, 0);
        accV[m][n] = __builtin_amdgcn_mfma_f32_16x16x32_bf16(af[m], vf[n], accV[m][n], 0, 0, 0);
      }
    __syncthreads();
    cur ^= 1;
  }

  const int h = (nBase >> 6) + wc;
  float bk4[4], bv4[4];
#pragma unroll
  for (int n = 0; n < 4; ++n) {
    bk4[n] = bkp[nBase + wc * 64 + n * 16 + lr];
    bv4[n] = bvp[nBase + wc * 64 + n * 16 + lr];
  }
  // K epilogue: rope, [b][h][t][d]
#pragma unroll
  for (int m = 0; m < 4; ++m) {
#pragma unroll
    for (int r = 0; r < 4; ++r) {
      const int gR = mBase + wr * 64 + m * 16 + lg * 4 + r;
      const int b2 = gR >> 12, p2 = gR & 4095;
      const int pos = ts[gR];
      const float* cp = cost + pos * 32;
      const float* sp = sint + pos * 32;
      const size_t obase = (((size_t)(b2 * NH_ + h)) * T_ + p2) * HD_;
#pragma unroll
      for (int n = 0; n < 2; ++n) {
        const int d = n * 16 + lr;
        const float x1 = accK[m][n][r] + bk4[n];
        const float x2 = accK[m][n + 2][r] + bk4[n + 2];
        const float c = cp[d], s = sp[d];
        Ko[obase + d] = f2bf(x1 * c - x2 * s);
        Ko[obase + d + 32] = f2bf(x2 * c + x1 * s);
      }
    }
  }
  // V epilogue: transpose, [b][h][d][t]
#pragma unroll
  for (int m = 0; m < 4; ++m) {
    const int r0 = mBase + wr * 64 + m * 16 + lg * 4;
    const int b = r0 >> 12, t = r0 & 4095;
#pragma unroll
    for (int n = 0; n < 4; ++n) {
      const int d = n * 16 + lr;
      ushort4 pk;
      pk.x = f2bf(accV[m][n][0] + bv4[n]);
      pk.y = f2bf(accV[m][n][1] + bv4[n]);
      pk.z = f2bf(accV[m][n][2] + bv4[n]);
      pk.w = f2bf(accV[m][n][3] + bv4[n]);
      *(ushort4*)(Vo + (((size_t)(b * NH_ + h)) * HD_ + d) * (size_t)T_ + t) = pk;
    }
  }
}

// Flash attention, T-split x2, swapped-operand QK^T and PV (lane-local rows).
// Grid 1024: (bh, lt, half), XCD-swizzled. 4 waves x 16 rows.
// Per lane: softmax row l = l0 + w*16 + lr; holds S^T[t = n*16+lg*4+r][l].
#define SCL 0.180336880111f  // 0.125 * log2(e)
__global__ __launch_bounds__(256, 4) void attn_half(
    const unsigned short* __restrict__ Q, const unsigned short* __restrict__ K,
    const unsigned short* __restrict__ V, const float* __restrict__ mbias,
    float* __restrict__ pws, float* __restrict__ mlws) {
  __shared__ u32x4 QP[512];     // 8KB: Q chunks; per-wave P (16x64 bf16) after
  __shared__ u32x4 Ks[2][512];  // 2x8KB: [kg 0..7][t 0..63]
  __shared__ u32x4 Vs[2][512];  // 2x8KB: [tg 0..7][d 0..63]
  const int tid = threadIdx.x, lane = tid & 63, w = tid >> 6;
  const int lr = lane & 15, lg = lane >> 4;
  const int orig = blockIdx.x;
  const int wg = (orig & 7) * 128 + (orig >> 3);  // bijective (1024 % 8 == 0)
  const int half = wg & 1, lt = (wg >> 1) & 7, bh = wg >> 4;
  const int b = bh >> 4;
  const int l0 = lt << 6;
  const int tBase = half << 11;  // 2048

#pragma unroll
  for (int i = 0; i < 2; ++i) {
    const int li = w * 2 + i;
    gload16(Q + ((size_t)bh * L_ + l0 + lane) * HD_ + li * 8, (unsigned short*)QP + li * 512);
  }
  __syncthreads();
  bf16x8 qf[2];
#pragma unroll
  for (int ks2 = 0; ks2 < 2; ++ks2)
    qf[ks2] = BC8(QP[(ks2 * 4 + lg) * 64 + w * 16 + lr]);
  // qf ds_reads drain at the next barrier (before any wave writes P into QP).

  f32x4 po[4];  // po[n][r] = O[l][d = n*16 + lg*4 + r]
#pragma unroll
  for (int n = 0; n < 4; ++n) po[n] = (f32x4){0.f, 0.f, 0.f, 0.f};
  float mrun = -1e30f, lrun = 0.f;

  char* Pw = (char*)QP + w * 2048;  // per-wave 16 rows x 128B, XOR-swizzled
  const int swz = (lr & 7) << 4;
  const float* mrow = mbias + (size_t)b * T_ + tBase;

  auto stage = [&](int bi, int it) {
    const int t0 = tBase + (it << 6);
#pragma unroll
    for (int i = 0; i < 2; ++i) {
      const int li = w * 2 + i;
      gload16(K + ((size_t)bh * T_ + t0 + lane) * HD_ + li * 8, (unsigned short*)Ks[bi] + li * 512);
      gload16(V + ((size_t)bh * HD_ + lane) * T_ + t0 + li * 8, (unsigned short*)Vs[bi] + li * 512);
    }
  };

  stage(0, 0);
  __syncthreads();
  int cur = 0;
  for (int it = 0; it < 32; ++it) {
    if (it < 31) stage(cur ^ 1, it + 1);  // prefetch overlaps this iter's compute
    const int t0l = it << 6;

    // S^T = K @ Q^T (swapped operands; same frag reads as before)
    f32x4 s[4];
#pragma unroll
    for (int n = 0; n < 4; ++n) s[n] = (f32x4){0.f, 0.f, 0.f, 0.f};
#pragma unroll
    for (int ks2 = 0; ks2 < 2; ++ks2) {
#pragma unroll
      for (int n = 0; n < 4; ++n) {
        bf16x8 kb = BC8(Ks[cur][(ks2 * 4 + lg) * 64 + n * 16 + lr]);
        s[n] = __builtin_amdgcn_mfma_f32_16x16x32_bf16(kb, qf[ks2], s[n], 0, 0, 0);
      }
    }
    // scale + mask bias (log2 domain); t = n*16 + lg*4 + r
#pragma unroll
    for (int n = 0; n < 4; ++n) {
      const f32x4 mb = *(const f32x4*)(mrow + t0l + n * 16 + lg * 4);
#pragma unroll
      for (int r = 0; r < 4; ++r) s[n][r] = s[n][r] * SCL + mb[r];
    }
    // row reduce: 15 in-lane fmax + 2 shfl
    f32x4 m4;
#pragma unroll
    for (int r = 0; r < 4; ++r)
      m4[r] = fmaxf(fmaxf(s[0][r], s[1][r]), fmaxf(s[2][r], s[3][r]));
    float x = fmaxf(fmaxf(m4[0], m4[1]), fmaxf(m4[2], m4[3]));
    x = fmaxf(x, __shfl_xor(x, 16));
    x = fmaxf(x, __shfl_xor(x, 32));
    const float mnew = fmaxf(mrun, x);
    const float sc = __builtin_exp2f(mrun - mnew);
    mrun = mnew;
    f32x4 ls4 = (f32x4){0.f, 0.f, 0.f, 0.f};
#pragma unroll
    for (int n = 0; n < 4; ++n)
#pragma unroll
      for (int r = 0; r < 4; ++r) {
        const float p = __builtin_exp2f(s[n][r] - mnew);
        s[n][r] = p;
        ls4[r] += p;
      }
    lrun = lrun * sc + ((ls4[0] + ls4[1]) + (ls4[2] + ls4[3]));
#pragma unroll
    for (int n = 0; n < 4; ++n) po[n] *= sc;
    // P^T -> per-wave LDS: row l(local)=lr, t = n*32..  (4 x b64, swizzled)
#pragma unroll
    for (int n = 0; n < 4; ++n) {
      uint2 pk;
      pk.x = cvtpk(s[n][0], s[n][1]);
      pk.y = cvtpk(s[n][2], s[n][3]);
      *(uint2*)(Pw + ((lr * 128 + n * 32 + lg * 8) ^ swz)) = pk;
    }
    // PV swapped: po[n] += V^T-frag x P^T-frag
    bf16x8 pa[2];
#pragma unroll
    for (int ks2 = 0; ks2 < 2; ++ks2)
      pa[ks2] = BC8(*(const u32x4*)(Pw + ((lr * 128 + ks2 * 64 + lg * 16) ^ swz)));
#pragma unroll
    for (int ks2 = 0; ks2 < 2; ++ks2) {
#pragma unroll
      for (int n = 0; n < 4; ++n) {
        bf16x8 vb = BC8(Vs[cur][(ks2 * 4 + lg) * 64 + n * 16 + lr]);
        po[n] = __builtin_amdgcn_mfma_f32_16x16x32_bf16(vb, pa[ks2], po[n], 0, 0, 0);
      }
    }
    __syncthreads();
    cur ^= 1;
  }

  // finalize: reduce lrun across lg, write partials
  lrun += __shfl_xor(lrun, 16);
  lrun += __shfl_xor(lrun, 32);
  const int l = w * 16 + lr;
  float* pbase = pws + ((size_t)(((bh << 3) + lt) * 2 + half)) * 4096;
  float* mlbase = mlws + ((size_t)(((bh << 3) + lt) * 2 + half)) * 128;
#pragma unroll
  for (int n = 0; n < 4; ++n)
    *(f32x4*)(pbase + l * 64 + n * 16 + lg * 4) = po[n];
  if (lg == 0) {
    mlbase[l * 2] = mrun;
    mlbase[l * 2 + 1] = lrun;
  }
}

// Combine the two T-halves. Grid 512 = (bh, lt), 256 thr.
__global__ void attn_combine(const float* __restrict__ pws, const float* __restrict__ mlws,
                             unsigned short* __restrict__ O) {
  const int blk = blockIdx.x;
  const int bh = blk >> 3, lt = blk & 7;
  const int b = bh >> 4, h = bh & 15;
  const int tid = threadIdx.x;
  const int row = tid >> 2, seg = tid & 3;  // 16 d's per thread
  const float* p0 = pws + ((size_t)blk * 2) * 4096 + row * 64 + seg * 16;
  const float* p1 = p0 + 4096;
  const float* ml0 = mlws + ((size_t)blk * 2) * 128 + row * 2;
  const float* ml1 = ml0 + 128;
  const float m0 = ml0[0], li0 = ml0[1], m1 = ml1[0], li1 = ml1[1];
  const float M = fmaxf(m0, m1);
  const float w0 = __builtin_exp2f(m0 - M), w1 = __builtin_exp2f(m1 - M);
  const float inv = 1.0f / (li0 * w0 + li1 * w1);
  const int gl = lt * 64 + row;
  unsigned short* orow = O + ((size_t)b * L_ + gl) * 1024 + h * HD_ + seg * 16;
#pragma unroll
  for (int j = 0; j < 4; ++j) {
    const float4 a = *(const float4*)(p0 + j * 4);
    const float4 c = *(const float4*)(p1 + j * 4);
    ushort4 pk;
    pk.x = f2bf((a.x * w0 + c.x * w1) * inv);
    pk.y = f2bf((a.y * w0 + c.y * w1) * inv);
    pk.z = f2bf((a.z * w0 + c.z * w1) * inv);
    pk.w = f2bf((a.w * w0 + c.w * w1) * inv);
    *(ushort4*)(orow + j * 4) = pk;
  }
}

extern "C" void kernel_launch(void* const* d_in, const int* in_sizes, int n_in,
                              void* d_out, int out_size, void* d_ws, size_t ws_size,
                              hipStream_t stream) {
  const float* latents = (const float*)d_in[0];
  const float* target = (const float*)d_in[1];
  const int* mask = (const int*)d_in[2];
  const int* ts = (const int*)d_in[3];
  const float* Wq = (const float*)d_in[4];
  const float* bq = (const float*)d_in[5];
  const float* Wk = (const float*)d_in[6];
  const float* bk = (const float*)d_in[7];
  const float* Wv = (const float*)d_in[8];
  const float* bv = (const float*)d_in[9];
  const float* Wo = (const float*)d_in[10];
  const float* bo = (const float*)d_in[11];
  float* out = (float*)d_out;

  // ws layout (117 MB total):
  char* ws = (char*)d_ws;
  float* cost = (float*)ws;                                    // 512 KB
  float* sint = (float*)(ws + (512 << 10));                    // 512 KB
  unsigned short* Qws = (unsigned short*)(ws + (1ull << 20));  // 4 MB  [b][h][l][d]
  unsigned short* Kws = (unsigned short*)(ws + (5ull << 20));  // 32 MB [b][h][t][d]
  unsigned short* Vws = (unsigned short*)(ws + (37ull << 20)); // 32 MB [b][h][d][t]
  // mbias overlays Ows head: written pre-GEMM, read by attn_half, dead before combine writes Ows
  float* mbias = (float*)(ws + (69ull << 20));                 // 64 KB
  unsigned short* Ows = (unsigned short*)(ws + (69ull << 20)); // 4 MB  [b*l][1024]
  unsigned short* latb = (unsigned short*)(ws + (73ull << 20));// 4 MB
  unsigned short* tgtb = (unsigned short*)(ws + (77ull << 20));// 32 MB (dead after gemm_kv)
  float* pws = (float*)(ws + (77ull << 20));                   // 16 MB (overlays tgtb)
  float* mlws = (float*)(ws + (93ull << 20));                  // 512 KB
  unsigned short* Wqb = (unsigned short*)(ws + (109ull << 20));// 2 MB
  unsigned short* Wkb = (unsigned short*)(ws + (111ull << 20));// 2 MB
  unsigned short* Wvb = (unsigned short*)(ws + (113ull << 20));// 2 MB
  unsigned short* Wob = (unsigned short*)(ws + (115ull << 20));// 2 MB

  CvtArgs ca;
  ca.src[0] = latents; ca.dst[0] = latb;
  ca.src[1] = target;  ca.dst[1] = tgtb;
  ca.src[2] = Wq;      ca.dst[2] = Wqb;
  ca.src[3] = Wk;      ca.dst[3] = Wkb;
  ca.src[4] = Wv;      ca.dst[4] = Wvb;
  ca.src[5] = Wo;      ca.dst[5] = Wob;
  const int nch[6] = {2097152 / 8, 16777216 / 8, 131072, 131072, 131072, 131072};
  ca.cum[0] = 0;
  for (int i = 0; i < 6; ++i) ca.cum[i + 1] = ca.cum[i] + nch[i];
  const int total = ca.cum[6];

  cvt_bf16<<<dim3(2048), dim3(256), 0, stream>>>(ca, total);
  rope_table<<<dim3(512), dim3(256), 0, stream>>>(cost, sint, mask, mbias);
  gemm_bf<0><<<dim3(16 * 8), dim3(256), 0, stream>>>(latb, Wqb, bq, Qws, cost, sint, nullptr);
  gemm_kv<<<dim3(1024), dim3(256), 0, stream>>>(tgtb, Wkb, Wvb, bk, bv, Kws, Vws, cost, sint, ts);
  attn_half<<<dim3(1024), dim3(256), 0, stream>>>(Qws, Kws, Vws, mbias, pws, mlws);
  attn_combine<<<dim3(512), dim3(256), 0, stream>>>(pws, mlws, Ows);
  gemm_bf<3><<<dim3(16 * 8), dim3(256), 0, stream>>>(Ows, Wob, bo, out, nullptr, nullptr, nullptr);
}

// Round 5
// 291.176 us; speedup vs baseline: 1.5995x; 1.0905x over previous
//
#include <hip/hip_runtime.h>

// Problem constants
#define B_ 4
#define L_ 512
#define T_ 4096
#define NH_ 16
#define HD_ 64
// HID = 1024, MAX_POS = 4096

using f32x4 = __attribute__((ext_vector_type(4))) float;
using bf16x8 = __attribute__((ext_vector_type(8))) short;
using u32x4 = __attribute__((ext_vector_type(4))) unsigned int;

__device__ __forceinline__ unsigned short f2bf(float x) {
  unsigned int u = __builtin_bit_cast(unsigned int, x);
  u += 0x7fffu + ((u >> 16) & 1u);
  return (unsigned short)(u >> 16);
}

__device__ __forceinline__ unsigned cvtpk(float lo, float hi) {
  unsigned r;
  asm("v_cvt_pk_bf16_f32 %0, %1, %2" : "=v"(r) : "v"(lo), "v"(hi));
  return r;
}

__device__ __forceinline__ u32x4 cvt8(const float4& a, const float4& b) {
  u32x4 r;
  r[0] = (unsigned)f2bf(a.x) | ((unsigned)f2bf(a.y) << 16);
  r[1] = (unsigned)f2bf(a.z) | ((unsigned)f2bf(a.w) << 16);
  r[2] = (unsigned)f2bf(b.x) | ((unsigned)f2bf(b.y) << 16);
  r[3] = (unsigned)f2bf(b.z) | ((unsigned)f2bf(b.w) << 16);
  return r;
}

__device__ __forceinline__ void gload16(const void* g, void* l) {
  __builtin_amdgcn_global_load_lds(
      (const __attribute__((address_space(1))) unsigned int*)g,
      (__attribute__((address_space(3))) unsigned int*)l, 16, 0, 0);
}

#define BC8(x) __builtin_bit_cast(bf16x8, (x))

// ---------------- f32 -> bf16 bulk convert (5 regions; target handled in-GEMM) ---
struct CvtArgs {
  const float* src[5];
  unsigned short* dst[5];
  int cum[6];  // cumulative chunk counts (chunk = 8 elems)
};

__global__ void cvt_bf16(CvtArgs a, int total) {
  for (int g = blockIdx.x * 256 + threadIdx.x; g < total; g += gridDim.x * 256) {
    int r = 0;
#pragma unroll
    for (int q = 0; q < 4; ++q) r += (g >= a.cum[q + 1]);
    const int lc = g - a.cum[r];
    const float4* s = (const float4*)a.src[r] + (size_t)lc * 2;
    float4 x0 = s[0], x1 = s[1];
    *((u32x4*)a.dst[r] + lc) = cvt8(x0, x1);
  }
}

// cos/sin tables [4096 pos][32] each + mask -> float bias (0 / -1e30)
__global__ void rope_table(float* __restrict__ cost, float* __restrict__ sint,
                           const int* __restrict__ mask, float* __restrict__ mbias) {
  const int idx = blockIdx.x * 256 + threadIdx.x;  // 4096*32 total
  const int pos = idx >> 5, i = idx & 31;
  const float inv = 1.0f / powf(10000.0f, (float)(2 * i) * (1.0f / 64.0f));
  const float f = (float)pos * inv;
  cost[idx] = cosf(f);
  sint[idx] = sinf(f);
  if (idx < B_ * T_) mbias[idx] = mask[idx] ? 0.f : -1e30f;
}

// C = A @ W.T + bias. A,W bf16 [rows][1024]. 128x128 tile, BK=32, 4 waves.
// EPI: 0=Q(rope->[b][h][l][d] bf16)  3=out(f32 row-major)
template <int EPI>
__global__ __launch_bounds__(256, 2) void gemm_bf(
    const unsigned short* __restrict__ A, const unsigned short* __restrict__ Wb,
    const float* __restrict__ bias, void* __restrict__ outp,
    const float* __restrict__ cost, const float* __restrict__ sint,
    const int* __restrict__ ts) {
  __shared__ u32x4 lsA[2][512];  // [buf][kg 0..3][row 0..127] chunks of 8 bf16
  __shared__ u32x4 lsB[2][512];
  const int tid = threadIdx.x;
  const int mt = blockIdx.x >> 3, nt = blockIdx.x & 7;
  const int mBase = mt << 7, nBase = nt << 7;
  const int lane = tid & 63, wid = tid >> 6;
  const int wr = wid >> 1, wc = wid & 1;
  const int lr = lane & 15, lg = lane >> 4;

  f32x4 acc[4][4];
#pragma unroll
  for (int m = 0; m < 4; ++m)
#pragma unroll
    for (int n = 0; n < 4; ++n) acc[m][n] = (f32x4){0.f, 0.f, 0.f, 0.f};

  auto stage = [&](int bi, int kt) {
    const int ko = kt * 32;
#pragma unroll
    for (int j2 = 0; j2 < 2; ++j2) {
      const int j = wid * 2 + j2;           // 0..7
      const int row = (j & 1) * 64 + lane;  // chunk j*64+lane = [kg=j>>1][row]
      const int kg = j >> 1;
      gload16(A + (size_t)(mBase + row) * 1024 + ko + kg * 8,
              (unsigned short*)lsA[bi] + j * 512);
      gload16(Wb + (size_t)(nBase + row) * 1024 + ko + kg * 8,
              (unsigned short*)lsB[bi] + j * 512);
    }
  };

  stage(0, 0);
  __syncthreads();
  int cur = 0;
  for (int kt = 0; kt < 32; ++kt) {
    if (kt < 31) stage(cur ^ 1, kt + 1);
    const u32x4* As = lsA[cur];
    const u32x4* Bs = lsB[cur];
    bf16x8 af[4], bfr[4];
#pragma unroll
    for (int m = 0; m < 4; ++m) af[m] = BC8(As[lg * 128 + wr * 64 + m * 16 + lr]);
#pragma unroll
    for (int n = 0; n < 4; ++n) bfr[n] = BC8(Bs[lg * 128 + wc * 64 + n * 16 + lr]);
#pragma unroll
    for (int m = 0; m < 4; ++m)
#pragma unroll
      for (int n = 0; n < 4; ++n)
        acc[m][n] = __builtin_amdgcn_mfma_f32_16x16x32_bf16(af[m], bfr[n], acc[m][n], 0, 0, 0);
    __syncthreads();
    cur ^= 1;
  }

  float bv[4];
#pragma unroll
  for (int n = 0; n < 4; ++n) bv[n] = bias[nBase + wc * 64 + n * 16 + lr];

  if (EPI == 3) {
    float* Of = (float*)outp;
#pragma unroll
    for (int m = 0; m < 4; ++m)
#pragma unroll
      for (int r = 0; r < 4; ++r) {
        const int gR = mBase + wr * 64 + m * 16 + lg * 4 + r;
#pragma unroll
        for (int n = 0; n < 4; ++n)
          Of[(size_t)gR * 1024 + nBase + wc * 64 + n * 16 + lr] = acc[m][n][r] + bv[n];
      }
  } else {
    unsigned short* Qo = (unsigned short*)outp;
    const int h = (nBase >> 6) + wc;
#pragma unroll
    for (int m = 0; m < 4; ++m) {
#pragma unroll
      for (int r = 0; r < 4; ++r) {
        const int gR = mBase + wr * 64 + m * 16 + lg * 4 + r;
        const int b2 = gR >> 9, p2 = gR & 511;
        const int pos = (int)(((float)p2 * 4095.0f) / 511.0f);  // matches jnp trunc
        const float* cp = cost + pos * 32;
        const float* sp = sint + pos * 32;
        const size_t obase = (((size_t)(b2 * NH_ + h)) * L_ + p2) * HD_;
#pragma unroll
        for (int n = 0; n < 2; ++n) {
          const int d = n * 16 + lr;
          const float x1 = acc[m][n][r] + bv[n];
          const float x2 = acc[m][n + 2][r] + bv[n + 2];
          const float c = cp[d], s = sp[d];
          Qo[obase + d] = f2bf(x1 * c - x2 * s);
          Qo[obase + d + 32] = f2bf(x2 * c + x1 * s);
        }
      }
    }
  }
}

// K+V projection as ONE GEMM: A(target, f32, converted in-flight) @ Wkv^T,
// Wkv = [Wk; Wv] bf16 [2048][1024]. 128x128 tile, 64-reg acc, 3 blocks/CU.
// nt<8 -> K epilogue (rope, [b][h][t][d]); nt>=8 -> V epilogue ([b][h][d][t]).
__global__ __launch_bounds__(256, 3) void gemm_kv2(
    const float* __restrict__ A, const unsigned short* __restrict__ Wkv,
    const float* __restrict__ bkp, const float* __restrict__ bvp,
    unsigned short* __restrict__ Ko, unsigned short* __restrict__ Vo,
    const float* __restrict__ cost, const float* __restrict__ sint,
    const int* __restrict__ ts) {
  __shared__ u32x4 lsA[2][512];
  __shared__ u32x4 lsB[2][512];
  const int tid = threadIdx.x;
  const int orig = blockIdx.x;
  const int wgid = (orig & 7) * 256 + (orig >> 3);  // bijective (2048 % 8 == 0)
  const int mt = wgid >> 4, nt = wgid & 15;
  const int mBase = mt << 7, nBase = nt << 7;
  const int lane = tid & 63, wid = tid >> 6;
  const int wr = wid >> 1, wc = wid & 1;
  const int lr = lane & 15, lg = lane >> 4;
  const int crow0 = tid >> 2, ckg = tid & 3;

  f32x4 acc[4][4];
#pragma unroll
  for (int m = 0; m < 4; ++m)
#pragma unroll
    for (int n = 0; n < 4; ++n) acc[m][n] = (f32x4){0.f, 0.f, 0.f, 0.f};

  const size_t arow0 = (size_t)(mBase + crow0) * 1024 + ckg * 8;
  const size_t arow1 = (size_t)(mBase + crow0 + 64) * 1024 + ckg * 8;
  const int dsti0 = ckg * 128 + crow0;
  const int dsti1 = ckg * 128 + crow0 + 64;

  auto stageW = [&](int bi, int kt) {
    const int ko = kt * 32;
#pragma unroll
    for (int j2 = 0; j2 < 2; ++j2) {
      const int j = wid * 2 + j2;
      const int row = (j & 1) * 64 + lane;
      const int kg = j >> 1;
      gload16(Wkv + (size_t)(nBase + row) * 1024 + ko + kg * 8,
              (unsigned short*)lsB[bi] + j * 512);
    }
  };

  // prologue: stage kt=0
  {
    float4 x0 = *(const float4*)(A + arow0), x1 = *(const float4*)(A + arow0 + 4);
    float4 x2 = *(const float4*)(A + arow1), x3 = *(const float4*)(A + arow1 + 4);
    lsA[0][dsti0] = cvt8(x0, x1);
    lsA[0][dsti1] = cvt8(x2, x3);
    stageW(0, 0);
  }
  __syncthreads();
  int cur = 0;
  for (int kt = 0; kt < 32; ++kt) {
    float4 fa0, fa1, fa2, fa3;
    const bool pre = (kt < 31);
    if (pre) {  // issue-early: f32 A loads + W gload_lds for kt+1
      const int ko = (kt + 1) * 32;
      fa0 = *(const float4*)(A + arow0 + ko);
      fa1 = *(const float4*)(A + arow0 + ko + 4);
      fa2 = *(const float4*)(A + arow1 + ko);
      fa3 = *(const float4*)(A + arow1 + ko + 4);
      stageW(cur ^ 1, kt + 1);
    }
    const u32x4* As = lsA[cur];
    const u32x4* Bs = lsB[cur];
    bf16x8 af[4], bfr[4];
#pragma unroll
    for (int m = 0; m < 4; ++m) af[m] = BC8(As[lg * 128 + wr * 64 + m * 16 + lr]);
#pragma unroll
    for (int n = 0; n < 4; ++n) bfr[n] = BC8(Bs[lg * 128 + wc * 64 + n * 16 + lr]);
#pragma unroll
    for (int m = 0; m < 4; ++m)
#pragma unroll
      for (int n = 0; n < 4; ++n)
        acc[m][n] = __builtin_amdgcn_mfma_f32_16x16x32_bf16(af[m], bfr[n], acc[m][n], 0, 0, 0);
    if (pre) {  // write-late: A kt+1 into the other buffer
      lsA[cur ^ 1][dsti0] = cvt8(fa0, fa1);
      lsA[cur ^ 1][dsti1] = cvt8(fa2, fa3);
    }
    __syncthreads();
    cur ^= 1;
  }

  // ---- epilogue: K (rope) or V (transpose) by n-range ----
  const bool isV = (nBase >= 1024);
  const int nb = isV ? (nBase - 1024) : nBase;
  const float* bp = isV ? bvp : bkp;
  const int h = (nb >> 6) + wc;
  float bb[4];
#pragma unroll
  for (int n = 0; n < 4; ++n) bb[n] = bp[nb + wc * 64 + n * 16 + lr];

  if (!isV) {
#pragma unroll
    for (int m = 0; m < 4; ++m) {
#pragma unroll
      for (int r = 0; r < 4; ++r) {
        const int gR = mBase + wr * 64 + m * 16 + lg * 4 + r;
        const int b2 = gR >> 12, p2 = gR & 4095;
        const int pos = ts[gR];
        const float* cp = cost + pos * 32;
        const float* sp = sint + pos * 32;
        const size_t obase = (((size_t)(b2 * NH_ + h)) * T_ + p2) * HD_;
#pragma unroll
        for (int n = 0; n < 2; ++n) {
          const int d = n * 16 + lr;
          const float x1 = acc[m][n][r] + bb[n];
          const float x2 = acc[m][n + 2][r] + bb[n + 2];
          const float c = cp[d], s = sp[d];
          Ko[obase + d] = f2bf(x1 * c - x2 * s);
          Ko[obase + d + 32] = f2bf(x2 * c + x1 * s);
        }
      }
    }
  } else {
#pragma unroll
    for (int m = 0; m < 4; ++m) {
      const int r0 = mBase + wr * 64 + m * 16 + lg * 4;
      const int b = r0 >> 12, t = r0 & 4095;
#pragma unroll
      for (int n = 0; n < 4; ++n) {
        const int d = n * 16 + lr;
        ushort4 pk;
        pk.x = f2bf(acc[m][n][0] + bb[n]);
        pk.y = f2bf(acc[m][n][1] + bb[n]);
        pk.z = f2bf(acc[m][n][2] + bb[n]);
        pk.w = f2bf(acc[m][n][3] + bb[n]);
        *(ushort4*)(Vo + (((size_t)(b * NH_ + h)) * HD_ + d) * (size_t)T_ + t) = pk;
      }
    }
  }
}

// Flash attention, T-split x2, swapped-operand QK^T and PV (lane-local rows).
// Grid 1024: (bh, lt, half), XCD-swizzled. 4 waves x 16 rows.
#define SCL 0.180336880111f  // 0.125 * log2(e)
__global__ __launch_bounds__(256, 4) void attn_half(
    const unsigned short* __restrict__ Q, const unsigned short* __restrict__ K,
    const unsigned short* __restrict__ V, const float* __restrict__ mbias,
    float* __restrict__ pws, float* __restrict__ mlws) {
  __shared__ u32x4 QP[512];     // 8KB: Q chunks; per-wave P (16x64 bf16) after
  __shared__ u32x4 Ks[2][512];  // 2x8KB: [kg 0..7][t 0..63]
  __shared__ u32x4 Vs[2][512];  // 2x8KB: [tg 0..7][d 0..63]
  const int tid = threadIdx.x, lane = tid & 63, w = tid >> 6;
  const int lr = lane & 15, lg = lane >> 4;
  const int orig = blockIdx.x;
  const int wg = (orig & 7) * 128 + (orig >> 3);  // bijective (1024 % 8 == 0)
  const int half = wg & 1, lt = (wg >> 1) & 7, bh = wg >> 4;
  const int b = bh >> 4;
  const int l0 = lt << 6;
  const int tBase = half << 11;  // 2048

#pragma unroll
  for (int i = 0; i < 2; ++i) {
    const int li = w * 2 + i;
    gload16(Q + ((size_t)bh * L_ + l0 + lane) * HD_ + li * 8, (unsigned short*)QP + li * 512);
  }
  __syncthreads();
  bf16x8 qf[2];
#pragma unroll
  for (int ks2 = 0; ks2 < 2; ++ks2)
    qf[ks2] = BC8(QP[(ks2 * 4 + lg) * 64 + w * 16 + lr]);
  // qf ds_reads drain at the next barrier (before any wave writes P into QP).

  f32x4 po[4];  // po[n][r] = O[l][d = n*16 + lg*4 + r]
#pragma unroll
  for (int n = 0; n < 4; ++n) po[n] = (f32x4){0.f, 0.f, 0.f, 0.f};
  float mrun = -1e30f, lrun = 0.f;

  char* Pw = (char*)QP + w * 2048;  // per-wave 16 rows x 128B, XOR-swizzled
  const int swz = (lr & 7) << 4;
  const float* mrow = mbias + (size_t)b * T_ + tBase;

  auto stage = [&](int bi, int it) {
    const int t0 = tBase + (it << 6);
#pragma unroll
    for (int i = 0; i < 2; ++i) {
      const int li = w * 2 + i;
      gload16(K + ((size_t)bh * T_ + t0 + lane) * HD_ + li * 8, (unsigned short*)Ks[bi] + li * 512);
      gload16(V + ((size_t)bh * HD_ + lane) * T_ + t0 + li * 8, (unsigned short*)Vs[bi] + li * 512);
    }
  };

  stage(0, 0);
  __syncthreads();
  int cur = 0;
  for (int it = 0; it < 32; ++it) {
    if (it < 31) stage(cur ^ 1, it + 1);  // prefetch overlaps this iter's compute
    const int t0l = it << 6;

    // S^T = K @ Q^T (swapped operands; same frag reads as before)
    f32x4 s[4];
#pragma unroll
    for (int n = 0; n < 4; ++n) s[n] = (f32x4){0.f, 0.f, 0.f, 0.f};
#pragma unroll
    for (int ks2 = 0; ks2 < 2; ++ks2) {
#pragma unroll
      for (int n = 0; n < 4; ++n) {
        bf16x8 kb = BC8(Ks[cur][(ks2 * 4 + lg) * 64 + n * 16 + lr]);
        s[n] = __builtin_amdgcn_mfma_f32_16x16x32_bf16(kb, qf[ks2], s[n], 0, 0, 0);
      }
    }
    // scale + mask bias (log2 domain); t = n*16 + lg*4 + r
#pragma unroll
    for (int n = 0; n < 4; ++n) {
      const f32x4 mb = *(const f32x4*)(mrow + t0l + n * 16 + lg * 4);
#pragma unroll
      for (int r = 0; r < 4; ++r) s[n][r] = s[n][r] * SCL + mb[r];
    }
    // row reduce: 15 in-lane fmax + 2 shfl
    f32x4 m4;
#pragma unroll
    for (int r = 0; r < 4; ++r)
      m4[r] = fmaxf(fmaxf(s[0][r], s[1][r]), fmaxf(s[2][r], s[3][r]));
    float x = fmaxf(fmaxf(m4[0], m4[1]), fmaxf(m4[2], m4[3]));
    x = fmaxf(x, __shfl_xor(x, 16));
    x = fmaxf(x, __shfl_xor(x, 32));
    const float mnew = fmaxf(mrun, x);
    const float sc = __builtin_exp2f(mrun - mnew);
    mrun = mnew;
    f32x4 ls4 = (f32x4){0.f, 0.f, 0.f, 0.f};
#pragma unroll
    for (int n = 0; n < 4; ++n)
#pragma unroll
      for (int r = 0; r < 4; ++r) {
        const float p = __builtin_exp2f(s[n][r] - mnew);
        s[n][r] = p;
        ls4[r] += p;
      }
    lrun = lrun * sc + ((ls4[0] + ls4[1]) + (ls4[2] + ls4[3]));
#pragma unroll
    for (int n = 0; n < 4; ++n) po[n] *= sc;
    // P^T -> per-wave LDS: row l(local)=lr, t = n*32..  (4 x b64, swizzled)
#pragma unroll
    for (int n = 0; n < 4; ++n) {
      uint2 pk;
      pk.x = cvtpk(s[n][0], s[n][1]);
      pk.y = cvtpk(s[n][2], s[n][3]);
      *(uint2*)(Pw + ((lr * 128 + n * 32 + lg * 8) ^ swz)) = pk;
    }
    // PV swapped: po[n] += V^T-frag x P^T-frag
    bf16x8 pa[2];
#pragma unroll
    for (int ks2 = 0; ks2 < 2; ++ks2)
      pa[ks2] = BC8(*(const u32x4*)(Pw + ((lr * 128 + ks2 * 64 + lg * 16) ^ swz)));
#pragma unroll
    for (int ks2 = 0; ks2 < 2; ++ks2) {
#pragma unroll
      for (int n = 0; n < 4; ++n) {
        bf16x8 vb = BC8(Vs[cur][(ks2 * 4 + lg) * 64 + n * 16 + lr]);
        po[n] = __builtin_amdgcn_mfma_f32_16x16x32_bf16(vb, pa[ks2], po[n], 0, 0, 0);
      }
    }
    __syncthreads();
    cur ^= 1;
  }

  // finalize: reduce lrun across lg, write partials
  lrun += __shfl_xor(lrun, 16);
  lrun += __shfl_xor(lrun, 32);
  const int l = w * 16 + lr;
  float* pbase = pws + ((size_t)(((bh << 3) + lt) * 2 + half)) * 4096;
  float* mlbase = mlws + ((size_t)(((bh << 3) + lt) * 2 + half)) * 128;
#pragma unroll
  for (int n = 0; n < 4; ++n)
    *(f32x4*)(pbase + l * 64 + n * 16 + lg * 4) = po[n];
  if (lg == 0) {
    mlbase[l * 2] = mrun;
    mlbase[l * 2 + 1] = lrun;
  }
}

// Combine the two T-halves. Grid 512 = (bh, lt), 256 thr.
__global__ void attn_combine(const float* __restrict__ pws, const float* __restrict__ mlws,
                             unsigned short* __restrict__ O) {
  const int blk = blockIdx.x;
  const int bh = blk >> 3, lt = blk & 7;
  const int b = bh >> 4, h = bh & 15;
  const int tid = threadIdx.x;
  const int row = tid >> 2, seg = tid & 3;  // 16 d's per thread
  const float* p0 = pws + ((size_t)blk * 2) * 4096 + row * 64 + seg * 16;
  const float* p1 = p0 + 4096;
  const float* ml0 = mlws + ((size_t)blk * 2) * 128 + row * 2;
  const float* ml1 = ml0 + 128;
  const float m0 = ml0[0], li0 = ml0[1], m1 = ml1[0], li1 = ml1[1];
  const float M = fmaxf(m0, m1);
  const float w0 = __builtin_exp2f(m0 - M), w1 = __builtin_exp2f(m1 - M);
  const float inv = 1.0f / (li0 * w0 + li1 * w1);
  const int gl = lt * 64 + row;
  unsigned short* orow = O + ((size_t)b * L_ + gl) * 1024 + h * HD_ + seg * 16;
#pragma unroll
  for (int j = 0; j < 4; ++j) {
    const float4 a = *(const float4*)(p0 + j * 4);
    const float4 c = *(const float4*)(p1 + j * 4);
    ushort4 pk;
    pk.x = f2bf((a.x * w0 + c.x * w1) * inv);
    pk.y = f2bf((a.y * w0 + c.y * w1) * inv);
    pk.z = f2bf((a.z * w0 + c.z * w1) * inv);
    pk.w = f2bf((a.w * w0 + c.w * w1) * inv);
    *(ushort4*)(orow + j * 4) = pk;
  }
}

extern "C" void kernel_launch(void* const* d_in, const int* in_sizes, int n_in,
                              void* d_out, int out_size, void* d_ws, size_t ws_size,
                              hipStream_t stream) {
  const float* latents = (const float*)d_in[0];
  const float* target = (const float*)d_in[1];
  const int* mask = (const int*)d_in[2];
  const int* ts = (const int*)d_in[3];
  const float* Wq = (const float*)d_in[4];
  const float* bq = (const float*)d_in[5];
  const float* Wk = (const float*)d_in[6];
  const float* bk = (const float*)d_in[7];
  const float* Wv = (const float*)d_in[8];
  const float* bv = (const float*)d_in[9];
  const float* Wo = (const float*)d_in[10];
  const float* bo = (const float*)d_in[11];
  float* out = (float*)d_out;

  // ws layout (117 MB total):
  char* ws = (char*)d_ws;
  float* cost = (float*)ws;                                    // 512 KB
  float* sint = (float*)(ws + (512 << 10));                    // 512 KB
  unsigned short* Qws = (unsigned short*)(ws + (1ull << 20));  // 4 MB  [b][h][l][d]
  unsigned short* Kws = (unsigned short*)(ws + (5ull << 20));  // 32 MB [b][h][t][d]
  unsigned short* Vws = (unsigned short*)(ws + (37ull << 20)); // 32 MB [b][h][d][t]
  // mbias overlays Ows head: written pre-GEMM, read by attn_half, dead before combine writes Ows
  float* mbias = (float*)(ws + (69ull << 20));                 // 64 KB
  unsigned short* Ows = (unsigned short*)(ws + (69ull << 20)); // 4 MB  [b*l][1024]
  unsigned short* latb = (unsigned short*)(ws + (73ull << 20));// 4 MB
  float* pws = (float*)(ws + (77ull << 20));                   // 16 MB
  float* mlws = (float*)(ws + (93ull << 20));                  // 512 KB
  unsigned short* Wqb = (unsigned short*)(ws + (109ull << 20));// 2 MB
  unsigned short* Wkvb = (unsigned short*)(ws + (111ull << 20));// 4 MB [Wk;Wv] [2048][1024]
  unsigned short* Wob = (unsigned short*)(ws + (115ull << 20));// 2 MB

  CvtArgs ca;
  ca.src[0] = latents; ca.dst[0] = latb;
  ca.src[1] = Wq;      ca.dst[1] = Wqb;
  ca.src[2] = Wk;      ca.dst[2] = Wkvb;                 // rows 0..1023
  ca.src[3] = Wv;      ca.dst[3] = Wkvb + (1 << 20);     // rows 1024..2047
  ca.src[4] = Wo;      ca.dst[4] = Wob;
  const int nch[5] = {2097152 / 8, 131072, 131072, 131072, 131072};
  ca.cum[0] = 0;
  for (int i = 0; i < 5; ++i) ca.cum[i + 1] = ca.cum[i] + nch[i];
  const int total = ca.cum[5];

  cvt_bf16<<<dim3(1024), dim3(256), 0, stream>>>(ca, total);
  rope_table<<<dim3(512), dim3(256), 0, stream>>>(cost, sint, mask, mbias);
  gemm_bf<0><<<dim3(16 * 8), dim3(256), 0, stream>>>(latb, Wqb, bq, Qws, cost, sint, nullptr);
  gemm_kv2<<<dim3(2048), dim3(256), 0, stream>>>(target, Wkvb, bk, bv, Kws, Vws, cost, sint, ts);
  attn_half<<<dim3(1024), dim3(256), 0, stream>>>(Qws, Kws, Vws, mbias, pws, mlws);
  attn_combine<<<dim3(512), dim3(256), 0, stream>>>(pws, mlws, Ows);
  gemm_bf<3><<<dim3(16 * 8), dim3(256), 0, stream>>>(Ows, Wob, bo, out, nullptr, nullptr, nullptr);
}